// Round 1
// baseline (647.143 us; speedup 1.0000x reference)
//
#include <hip/hip_runtime.h>
#include <math.h>

#define NN 50000
#define NE 800000
#define INCH 128
#define HID1 16
#define H1 4
#define C1 64      /* HEADS*HID */
#define C2 32
#define NEG 0.2f
#define EPSF 1e-16f

// order-preserving float<->unsigned encoding for atomicMax on floats
static __device__ __forceinline__ unsigned fenc(float f){
    unsigned u = __float_as_uint(f);
    return (u & 0x80000000u) ? ~u : (u | 0x80000000u);
}
static __device__ __forceinline__ float fdec(unsigned u){
    return (u & 0x80000000u) ? __uint_as_float(u & 0x7FFFFFFFu) : __uint_as_float(~u);
}
static __device__ __forceinline__ float lrelu(float v){ return v > 0.f ? v : NEG * v; }

// ---------------- layer 1 ----------------

__global__ void k_init1(float* agg1, unsigned* m1, float* den1){
    int i = blockIdx.x * 256 + threadIdx.x;
    if (i < NN * C1) agg1[i] = 0.f;
    if (i < NN * H1){ m1[i] = 0u; den1[i] = 0.f; }
}

__global__ void k_gemm1(const float* __restrict__ x, const float* __restrict__ W,
                        float* __restrict__ h){
    int c = threadIdx.x & 63;
    int node = blockIdx.x * 4 + (threadIdx.x >> 6);
    if (node >= NN) return;
    const float* xr = x + (size_t)node * INCH;
    float acc = 0.f;
    #pragma unroll 8
    for (int k = 0; k < INCH; ++k) acc = fmaf(xr[k], W[k * C1 + c], acc);
    h[(size_t)node * C1 + c] = acc;
}

__global__ void k_alpha1(const float* __restrict__ h, const float* __restrict__ asrc,
                         const float* __restrict__ adst, float* as, float* ad){
    int i = blockIdx.x * 256 + threadIdx.x;   // node*H1 + head
    if (i >= NN * H1) return;
    int node = i >> 2, hd = i & 3;
    const float* hr = h + (size_t)node * C1 + hd * HID1;
    float sa = 0.f, da = 0.f;
    #pragma unroll
    for (int c = 0; c < HID1; ++c){
        float v = hr[c];
        sa = fmaf(v, asrc[hd * HID1 + c], sa);
        da = fmaf(v, adst[hd * HID1 + c], da);
    }
    as[i] = sa; ad[i] = da;
}

__global__ void k_emax1(const int* __restrict__ ei, const float* __restrict__ as,
                        const float* __restrict__ ad, unsigned* m){
    int i = blockIdx.x * 256 + threadIdx.x;   // edge*H1 + head
    if (i >= NE * H1) return;
    int e = i >> 2, hd = i & 3;
    int s = ei[e], d = ei[NE + e];
    float v = lrelu(as[s * H1 + hd] + ad[d * H1 + hd]);
    atomicMax(&m[d * H1 + hd], fenc(v));
}

__global__ void k_eexp1(const int* __restrict__ ei, const float* __restrict__ as,
                        const float* __restrict__ ad, const unsigned* __restrict__ m,
                        float* __restrict__ e1, float* den){
    int i = blockIdx.x * 256 + threadIdx.x;
    if (i >= NE * H1) return;
    int e = i >> 2, hd = i & 3;
    int s = ei[e], d = ei[NE + e];
    float v = lrelu(as[s * H1 + hd] + ad[d * H1 + hd]);
    float ex = expf(v - fdec(m[d * H1 + hd]));
    e1[i] = ex;
    atomicAdd(&den[d * H1 + hd], ex);
}

__global__ void k_escat1(const int* __restrict__ ei, const float* __restrict__ h,
                         const float* __restrict__ e1, const float* __restrict__ den,
                         float* agg){
    int gid = blockIdx.x * 256 + threadIdx.x;   // edge*64 + channel
    int e = gid >> 6, hc = gid & 63;
    if (e >= NE) return;
    int s = ei[e], d = ei[NE + e];
    int hd = hc >> 4;
    float alpha = e1[e * H1 + hd] / (den[d * H1 + hd] + EPSF);
    atomicAdd(&agg[(size_t)d * C1 + hc], h[(size_t)s * C1 + hc] * alpha);
}

__global__ void k_elu1(float* agg, const float* __restrict__ b1){
    int i = blockIdx.x * 256 + threadIdx.x;
    if (i >= NN * C1) return;
    float v = agg[i] + b1[i & 63];
    agg[i] = v > 0.f ? v : expm1f(v);
}

// ---------------- layer 2 ----------------

__global__ void k_gemm2(const float* __restrict__ hp, const float* __restrict__ W2,
                        float* __restrict__ h2){
    int c = threadIdx.x & 31;
    int node = blockIdx.x * 8 + (threadIdx.x >> 5);
    if (node >= NN) return;
    const float* hr = hp + (size_t)node * C1;
    float acc = 0.f;
    #pragma unroll 8
    for (int k = 0; k < C1; ++k) acc = fmaf(hr[k], W2[k * C2 + c], acc);
    h2[(size_t)node * C2 + c] = acc;
}

__global__ void k_alpha2(const float* __restrict__ h2, const float* __restrict__ asrc,
                         const float* __restrict__ adst, float* as, float* ad,
                         unsigned* m, float* den){
    int i = blockIdx.x * 256 + threadIdx.x;   // node
    if (i >= NN) return;
    const float* hr = h2 + (size_t)i * C2;
    float sa = 0.f, da = 0.f;
    #pragma unroll
    for (int c = 0; c < C2; ++c){
        float v = hr[c];
        sa = fmaf(v, asrc[c], sa);
        da = fmaf(v, adst[c], da);
    }
    as[i] = sa; ad[i] = da; m[i] = 0u; den[i] = 0.f;
}

__global__ void k_initout(float* out, const float* __restrict__ b2){
    int i = blockIdx.x * 256 + threadIdx.x;
    if (i < NN * C2) out[i] = b2[i & 31];
}

__global__ void k_emax2(const int* __restrict__ ei, const float* __restrict__ as,
                        const float* __restrict__ ad, unsigned* m){
    int e = blockIdx.x * 256 + threadIdx.x;
    if (e >= NE) return;
    int s = ei[e], d = ei[NE + e];
    float v = lrelu(as[s] + ad[d]);
    atomicMax(&m[d], fenc(v));
}

__global__ void k_eexp2(const int* __restrict__ ei, const float* __restrict__ as,
                        const float* __restrict__ ad, const unsigned* __restrict__ m,
                        float* __restrict__ e2, float* den){
    int e = blockIdx.x * 256 + threadIdx.x;
    if (e >= NE) return;
    int s = ei[e], d = ei[NE + e];
    float v = lrelu(as[s] + ad[d]);
    float ex = expf(v - fdec(m[d]));
    e2[e] = ex;
    atomicAdd(&den[d], ex);
}

__global__ void k_escat2(const int* __restrict__ ei, const float* __restrict__ h2,
                         const float* __restrict__ e2, const float* __restrict__ den,
                         float* out){
    int gid = blockIdx.x * 256 + threadIdx.x;   // edge*32 + channel
    int e = gid >> 5, c = gid & 31;
    if (e >= NE) return;
    int s = ei[e], d = ei[NE + e];
    float alpha = e2[e] / (den[d] + EPSF);
    atomicAdd(&out[(size_t)d * C2 + c], h2[(size_t)s * C2 + c] * alpha);
}

extern "C" void kernel_launch(void* const* d_in, const int* in_sizes, int n_in,
                              void* d_out, int out_size, void* d_ws, size_t ws_size,
                              hipStream_t stream) {
    const float* x    = (const float*)d_in[0];
    const int*   ei   = (const int*)  d_in[1];
    const float* W1   = (const float*)d_in[2];
    const float* as1w = (const float*)d_in[3];
    const float* ad1w = (const float*)d_in[4];
    const float* b1   = (const float*)d_in[5];
    const float* W2   = (const float*)d_in[6];
    const float* as2w = (const float*)d_in[7];
    const float* ad2w = (const float*)d_in[8];
    const float* b2   = (const float*)d_in[9];
    float* out = (float*)d_out;

    float* p = (float*)d_ws;
    float* h1   = p; p += (size_t)NN * C1;
    float* agg1 = p; p += (size_t)NN * C1;
    float* as1  = p; p += (size_t)NN * H1;
    float* ad1  = p; p += (size_t)NN * H1;
    unsigned* m1 = (unsigned*)p; p += (size_t)NN * H1;
    float* den1 = p; p += (size_t)NN * H1;
    float* e1   = p; p += (size_t)NE * H1;
    float* h2   = p; p += (size_t)NN * C2;
    float* as2  = p; p += NN;
    float* ad2  = p; p += NN;
    unsigned* m2 = (unsigned*)p; p += NN;
    float* den2 = p; p += NN;
    float* e2   = p; p += NE;

    dim3 B(256);
    k_init1 <<<(NN * C1 + 255) / 256, B, 0, stream>>>(agg1, m1, den1);
    k_gemm1 <<<(NN + 3) / 4, B, 0, stream>>>(x, W1, h1);
    k_alpha1<<<(NN * H1 + 255) / 256, B, 0, stream>>>(h1, as1w, ad1w, as1, ad1);
    k_emax1 <<<(NE * H1 + 255) / 256, B, 0, stream>>>(ei, as1, ad1, m1);
    k_eexp1 <<<(NE * H1 + 255) / 256, B, 0, stream>>>(ei, as1, ad1, m1, e1, den1);
    k_escat1<<<(NE * C1 + 255) / 256, B, 0, stream>>>(ei, h1, e1, den1, agg1);
    k_elu1  <<<(NN * C1 + 255) / 256, B, 0, stream>>>(agg1, b1);
    k_gemm2 <<<(NN + 7) / 8, B, 0, stream>>>(agg1, W2, h2);
    k_alpha2<<<(NN + 255) / 256, B, 0, stream>>>(h2, as2w, ad2w, as2, ad2, m2, den2);
    k_initout<<<(NN * C2 + 255) / 256, B, 0, stream>>>(out, b2);
    k_emax2 <<<(NE + 255) / 256, B, 0, stream>>>(ei, as2, ad2, m2);
    k_eexp2 <<<(NE + 255) / 256, B, 0, stream>>>(ei, as2, ad2, m2, e2, den2);
    k_escat2<<<(NE * C2 + 255) / 256, B, 0, stream>>>(ei, h2, e2, den2, out);
}

// Round 2
// 395.851 us; speedup vs baseline: 1.6348x; 1.6348x over previous
//
#include <hip/hip_runtime.h>
#include <math.h>

#define NN 50000
#define NE 800000
#define INCH 128
#define HID1 16
#define H1 4
#define C1 64      /* HEADS*HID */
#define C2 32
#define NEG 0.2f
#define EPSF 1e-16f
#define NB 196     /* ceil(NN/256) */

static __device__ __forceinline__ float lrelu(float v){ return v > 0.f ? v : NEG * v; }

// ---------------- CSR build (dst-sorted) ----------------

__global__ void k_zero(int* deg){
    int i = blockIdx.x * 256 + threadIdx.x;
    if (i < NN) deg[i] = 0;
}

__global__ void k_deg(const int* __restrict__ ei, int* deg){
    int e = blockIdx.x * 256 + threadIdx.x;
    if (e < NE) atomicAdd(&deg[ei[NE + e]], 1);
}

__global__ void k_scanA(const int* __restrict__ deg, int* rows, int* bsum){
    __shared__ int sh[256];
    int i = blockIdx.x * 256 + threadIdx.x;
    int v = (i < NN) ? deg[i] : 0;
    sh[threadIdx.x] = v;
    __syncthreads();
    int val = v;
    for (int off = 1; off < 256; off <<= 1){
        int t = (threadIdx.x >= off) ? sh[threadIdx.x - off] : 0;
        __syncthreads();
        val += t;
        sh[threadIdx.x] = val;
        __syncthreads();
    }
    if (i < NN) rows[i] = val - v;                 // exclusive
    if (threadIdx.x == 255) bsum[blockIdx.x] = val; // block total
}

__global__ void k_scanB(int* bsum){
    __shared__ int sh[256];
    int v = (threadIdx.x < NB) ? bsum[threadIdx.x] : 0;
    sh[threadIdx.x] = v;
    __syncthreads();
    int val = v;
    for (int off = 1; off < 256; off <<= 1){
        int t = (threadIdx.x >= off) ? sh[threadIdx.x - off] : 0;
        __syncthreads();
        val += t;
        sh[threadIdx.x] = val;
        __syncthreads();
    }
    if (threadIdx.x < NB) bsum[threadIdx.x] = val - v; // exclusive
}

__global__ void k_scanC(int* rows, const int* __restrict__ bsum, int* cur){
    int i = blockIdx.x * 256 + threadIdx.x;
    if (i < NN){
        int r = rows[i] + bsum[blockIdx.x];
        rows[i] = r;
        cur[i] = r;
    }
}

__global__ void k_bucket(const int* __restrict__ ei, int* cur, int* srcs){
    int e = blockIdx.x * 256 + threadIdx.x;
    if (e >= NE) return;
    int d = ei[NE + e];
    int pos = atomicAdd(&cur[d], 1);
    srcs[pos] = ei[e];
}

// ---------------- layer 1 ----------------

__global__ void k_gemm1(const float* __restrict__ x, const float* __restrict__ W,
                        float* __restrict__ h){
    int c = threadIdx.x & 63;
    int node = blockIdx.x * 4 + (threadIdx.x >> 6);
    if (node >= NN) return;
    const float* xr = x + (size_t)node * INCH;
    float acc = 0.f;
    #pragma unroll 8
    for (int k = 0; k < INCH; ++k) acc = fmaf(xr[k], W[k * C1 + c], acc);
    h[(size_t)node * C1 + c] = acc;
}

__global__ void k_alpha1(const float* __restrict__ h, const float* __restrict__ asrc,
                         const float* __restrict__ adst, float* as, float* ad){
    int i = blockIdx.x * 256 + threadIdx.x;   // node*H1 + head
    if (i >= NN * H1) return;
    int node = i >> 2, hd = i & 3;
    const float* hr = h + (size_t)node * C1 + hd * HID1;
    float sa = 0.f, da = 0.f;
    #pragma unroll
    for (int c = 0; c < HID1; ++c){
        float v = hr[c];
        sa = fmaf(v, asrc[hd * HID1 + c], sa);
        da = fmaf(v, adst[hd * HID1 + c], da);
    }
    as[i] = sa; ad[i] = da;
}

// one 64-lane wave per dst node: lane = channel c (head = c>>4)
__global__ void k_agg1(const int* __restrict__ srcs, const int* __restrict__ rows,
                       const int* __restrict__ deg, const float* __restrict__ h,
                       const float* __restrict__ as, const float* __restrict__ ad,
                       const float* __restrict__ b1, float* __restrict__ hp){
    int node = blockIdx.x * 4 + (threadIdx.x >> 6);
    if (node >= NN) return;
    int lane = threadIdx.x & 63;
    int hd = lane >> 4;
    int sub = lane & 15;
    int start = rows[node], dg = deg[node];
    float adv = ad[node * H1 + hd];

    // pass 1: online softmax (16 lanes per head, strided over edges)
    float m = -1e30f, ssum = 0.f;
    for (int j = sub; j < dg; j += 16){
        int s = srcs[start + j];
        float v = lrelu(as[s * H1 + hd] + adv);
        float nm = fmaxf(m, v);
        ssum = ssum * __expf(m - nm) + __expf(v - nm);
        m = nm;
    }
    #pragma unroll
    for (int off = 1; off < 16; off <<= 1){
        float om = __shfl_xor(m, off);
        float os = __shfl_xor(ssum, off);
        float nm = fmaxf(m, om);
        ssum = ssum * __expf(m - nm) + os * __expf(om - nm);
        m = nm;
    }
    float inv = 1.f / (ssum + EPSF);

    // pass 2: gather h[src] (coalesced 256B/edge), 2-edge unroll for MLP
    float acc = 0.f;
    int j = 0;
    for (; j + 1 < dg; j += 2){
        int s0 = srcs[start + j], s1 = srcs[start + j + 1];
        float v0 = lrelu(as[s0 * H1 + hd] + adv);
        float v1 = lrelu(as[s1 * H1 + hd] + adv);
        float h0 = h[(size_t)s0 * C1 + lane];
        float hv = h[(size_t)s1 * C1 + lane];
        acc = fmaf(h0, __expf(v0 - m) * inv, acc);
        acc = fmaf(hv, __expf(v1 - m) * inv, acc);
    }
    if (j < dg){
        int s = srcs[start + j];
        float v = lrelu(as[s * H1 + hd] + adv);
        acc = fmaf(h[(size_t)s * C1 + lane], __expf(v - m) * inv, acc);
    }
    float o = acc + b1[lane];
    hp[(size_t)node * C1 + lane] = o > 0.f ? o : expm1f(o);   // fused bias+ELU
}

// ---------------- layer 2 ----------------

__global__ void k_gemm2(const float* __restrict__ hp, const float* __restrict__ W2,
                        float* __restrict__ h2){
    int c = threadIdx.x & 31;
    int node = blockIdx.x * 8 + (threadIdx.x >> 5);
    if (node >= NN) return;
    const float* hr = hp + (size_t)node * C1;
    float acc = 0.f;
    #pragma unroll 8
    for (int k = 0; k < C1; ++k) acc = fmaf(hr[k], W2[k * C2 + c], acc);
    h2[(size_t)node * C2 + c] = acc;
}

__global__ void k_alpha2(const float* __restrict__ h2, const float* __restrict__ asrc,
                         const float* __restrict__ adst, float* as, float* ad){
    int i = blockIdx.x * 256 + threadIdx.x;   // node
    if (i >= NN) return;
    const float* hr = h2 + (size_t)i * C2;
    float sa = 0.f, da = 0.f;
    #pragma unroll
    for (int c = 0; c < C2; ++c){
        float v = hr[c];
        sa = fmaf(v, asrc[c], sa);
        da = fmaf(v, adst[c], da);
    }
    as[i] = sa; ad[i] = da;
}

// two nodes per wave: 32 lanes per node, lane = channel c
__global__ void k_agg2(const int* __restrict__ srcs, const int* __restrict__ rows,
                       const int* __restrict__ deg, const float* __restrict__ h2,
                       const float* __restrict__ as, const float* __restrict__ ad,
                       const float* __restrict__ b2, float* __restrict__ out){
    int node = blockIdx.x * 8 + (threadIdx.x >> 5);
    if (node >= NN) return;
    int lane = threadIdx.x & 31;
    int start = rows[node], dg = deg[node];
    float adv = ad[node];

    float m = -1e30f, ssum = 0.f;
    for (int j = lane; j < dg; j += 32){
        int s = srcs[start + j];
        float v = lrelu(as[s] + adv);
        float nm = fmaxf(m, v);
        ssum = ssum * __expf(m - nm) + __expf(v - nm);
        m = nm;
    }
    #pragma unroll
    for (int off = 1; off < 32; off <<= 1){
        float om = __shfl_xor(m, off);
        float os = __shfl_xor(ssum, off);
        float nm = fmaxf(m, om);
        ssum = ssum * __expf(m - nm) + os * __expf(om - nm);
        m = nm;
    }
    float inv = 1.f / (ssum + EPSF);

    float acc = 0.f;
    int j = 0;
    for (; j + 1 < dg; j += 2){
        int s0 = srcs[start + j], s1 = srcs[start + j + 1];
        float v0 = lrelu(as[s0] + adv);
        float v1 = lrelu(as[s1] + adv);
        float h0 = h2[(size_t)s0 * C2 + lane];
        float hv = h2[(size_t)s1 * C2 + lane];
        acc = fmaf(h0, __expf(v0 - m) * inv, acc);
        acc = fmaf(hv, __expf(v1 - m) * inv, acc);
    }
    if (j < dg){
        int s = srcs[start + j];
        acc = fmaf(h2[(size_t)s * C2 + lane], __expf(lrelu(as[s] + adv) - m) * inv, acc);
    }
    out[(size_t)node * C2 + lane] = acc + b2[lane];
}

extern "C" void kernel_launch(void* const* d_in, const int* in_sizes, int n_in,
                              void* d_out, int out_size, void* d_ws, size_t ws_size,
                              hipStream_t stream) {
    const float* x    = (const float*)d_in[0];
    const int*   ei   = (const int*)  d_in[1];
    const float* W1   = (const float*)d_in[2];
    const float* as1w = (const float*)d_in[3];
    const float* ad1w = (const float*)d_in[4];
    const float* b1   = (const float*)d_in[5];
    const float* W2   = (const float*)d_in[6];
    const float* as2w = (const float*)d_in[7];
    const float* ad2w = (const float*)d_in[8];
    const float* b2   = (const float*)d_in[9];
    float* out = (float*)d_out;

    float* p = (float*)d_ws;
    float* h1   = p; p += (size_t)NN * C1;
    float* hp   = p; p += (size_t)NN * C1;
    float* as1  = p; p += (size_t)NN * H1;
    float* ad1  = p; p += (size_t)NN * H1;
    float* h2   = p; p += (size_t)NN * C2;
    float* as2  = p; p += NN;
    float* ad2  = p; p += NN;
    int* deg  = (int*)p; p += NN;
    int* rows = (int*)p; p += NN;
    int* cur  = (int*)p; p += NN;
    int* srcs = (int*)p; p += NE;
    int* bsum = (int*)p; p += 256;

    dim3 B(256);
    // CSR build
    k_zero  <<<NB, B, 0, stream>>>(deg);
    k_deg   <<<(NE + 255) / 256, B, 0, stream>>>(ei, deg);
    k_scanA <<<NB, B, 0, stream>>>(deg, rows, bsum);
    k_scanB <<<1, B, 0, stream>>>(bsum);
    k_scanC <<<NB, B, 0, stream>>>(rows, bsum, cur);
    k_bucket<<<(NE + 255) / 256, B, 0, stream>>>(ei, cur, srcs);
    // layer 1
    k_gemm1 <<<(NN + 3) / 4, B, 0, stream>>>(x, W1, h1);
    k_alpha1<<<(NN * H1 + 255) / 256, B, 0, stream>>>(h1, as1w, ad1w, as1, ad1);
    k_agg1  <<<(NN + 3) / 4, B, 0, stream>>>(srcs, rows, deg, h1, as1, ad1, b1, hp);
    // layer 2
    k_gemm2 <<<(NN + 7) / 8, B, 0, stream>>>(hp, W2, h2);
    k_alpha2<<<(NN + 255) / 256, B, 0, stream>>>(h2, as2w, ad2w, as2, ad2);
    k_agg2  <<<(NN + 7) / 8, B, 0, stream>>>(srcs, rows, deg, h2, as2, ad2, b2, out);
}

// Round 3
// 310.737 us; speedup vs baseline: 2.0826x; 1.2739x over previous
//
#include <hip/hip_runtime.h>
#include <math.h>

#define NN 50000
#define NE 800000
#define INCH 128
#define HID1 16
#define H1 4
#define C1 64      /* HEADS*HID */
#define C2 32
#define NEG 0.2f
#define EPSF 1e-16f
#define NB 196     /* ceil(NN/256) */

static __device__ __forceinline__ float lrelu(float v){ return v > 0.f ? v : NEG * v; }

// ---------------- CSR build (dst-sorted) ----------------

__global__ void k_zero(int* deg){
    int i = blockIdx.x * 256 + threadIdx.x;
    if (i < NN) deg[i] = 0;
}

__global__ void k_deg(const int* __restrict__ ei, int* deg){
    int e = blockIdx.x * 256 + threadIdx.x;
    if (e < NE) atomicAdd(&deg[ei[NE + e]], 1);
}

__global__ void k_scanA(const int* __restrict__ deg, int* rows, int* bsum){
    __shared__ int sh[256];
    int i = blockIdx.x * 256 + threadIdx.x;
    int v = (i < NN) ? deg[i] : 0;
    sh[threadIdx.x] = v;
    __syncthreads();
    int val = v;
    for (int off = 1; off < 256; off <<= 1){
        int t = (threadIdx.x >= off) ? sh[threadIdx.x - off] : 0;
        __syncthreads();
        val += t;
        sh[threadIdx.x] = val;
        __syncthreads();
    }
    if (i < NN) rows[i] = val - v;                 // exclusive
    if (threadIdx.x == 255) bsum[blockIdx.x] = val; // block total
}

__global__ void k_scanB(int* bsum){
    __shared__ int sh[256];
    int v = (threadIdx.x < NB) ? bsum[threadIdx.x] : 0;
    sh[threadIdx.x] = v;
    __syncthreads();
    int val = v;
    for (int off = 1; off < 256; off <<= 1){
        int t = (threadIdx.x >= off) ? sh[threadIdx.x - off] : 0;
        __syncthreads();
        val += t;
        sh[threadIdx.x] = val;
        __syncthreads();
    }
    if (threadIdx.x < NB) bsum[threadIdx.x] = val - v; // exclusive
}

__global__ void k_scanC(int* rows, const int* __restrict__ bsum, int* cur){
    int i = blockIdx.x * 256 + threadIdx.x;
    if (i < NN){
        int r = rows[i] + bsum[blockIdx.x];
        rows[i] = r;
        cur[i] = r;
    }
}

__global__ void k_bucket(const int* __restrict__ ei, int* cur, int* srcs){
    int e = blockIdx.x * 256 + threadIdx.x;
    if (e >= NE) return;
    int d = ei[NE + e];
    int pos = atomicAdd(&cur[d], 1);
    srcs[pos] = ei[e];
}

// ---------------- GEMM 1: [NN,128] x [128,64], LDS-tiled 64x64 ----------------
// block: 256 threads, 64 nodes x 64 ch; 16 outputs/thread (4 nodes x 4 ch)

__global__ void k_gemm1(const float* __restrict__ x, const float* __restrict__ W,
                        float* __restrict__ h){
    __shared__ float XT[INCH][68];      // [k][node], pad 68 for bank spread
    __shared__ float WS[INCH * C1];     // [k][ch] row-major

    int t = threadIdx.x;
    int nodeL = t >> 2;                 // 0..63
    int kc = t & 3;                     // k-chunk
    int g = blockIdx.x * 64 + nodeL;
    int gc = min(g, NN - 1);
    const float4* xr = (const float4*)(x + (size_t)gc * INCH);
    #pragma unroll
    for (int i = 0; i < 8; ++i){
        int k = kc * 32 + i * 4;
        float4 v = xr[k >> 2];
        XT[k + 0][nodeL] = v.x;
        XT[k + 1][nodeL] = v.y;
        XT[k + 2][nodeL] = v.z;
        XT[k + 3][nodeL] = v.w;
    }
    const float4* W4 = (const float4*)W;
    float4* WS4 = (float4*)WS;
    #pragma unroll
    for (int i = 0; i < 8; ++i) WS4[i * 256 + t] = W4[i * 256 + t];
    __syncthreads();

    int tx = t & 15, ty = t >> 4;       // ch group, node group
    int c4 = tx * 4, n4 = ty * 4;
    float acc[4][4];
    #pragma unroll
    for (int a = 0; a < 4; ++a)
        #pragma unroll
        for (int b = 0; b < 4; ++b) acc[a][b] = 0.f;

    #pragma unroll 8
    for (int k = 0; k < INCH; ++k){
        float4 xa = *(const float4*)&XT[k][n4];
        float4 wb = *(const float4*)&WS[k * C1 + c4];
        const float xv[4] = {xa.x, xa.y, xa.z, xa.w};
        const float wv[4] = {wb.x, wb.y, wb.z, wb.w};
        #pragma unroll
        for (int a = 0; a < 4; ++a)
            #pragma unroll
            for (int b = 0; b < 4; ++b)
                acc[a][b] = fmaf(xv[a], wv[b], acc[a][b]);
    }

    #pragma unroll
    for (int a = 0; a < 4; ++a){
        int n = blockIdx.x * 64 + n4 + a;
        if (n < NN){
            float4 o = {acc[a][0], acc[a][1], acc[a][2], acc[a][3]};
            *(float4*)&h[(size_t)n * C1 + c4] = o;
        }
    }
}

// ---------------- GEMM 2: [NN,64] x [64,32], LDS-tiled 128x32 ----------------

__global__ void k_gemm2(const float* __restrict__ hp, const float* __restrict__ W2,
                        float* __restrict__ h2){
    __shared__ float XT[C1][132];       // [k][node], pad 132
    __shared__ float WS[C1 * C2];

    int t = threadIdx.x;
    int nodeL = t >> 1;                 // 0..127
    int kc = t & 1;
    int g = blockIdx.x * 128 + nodeL;
    int gc = min(g, NN - 1);
    const float4* xr = (const float4*)(hp + (size_t)gc * C1);
    #pragma unroll
    for (int i = 0; i < 8; ++i){
        int k = kc * 32 + i * 4;
        float4 v = xr[k >> 2];
        XT[k + 0][nodeL] = v.x;
        XT[k + 1][nodeL] = v.y;
        XT[k + 2][nodeL] = v.z;
        XT[k + 3][nodeL] = v.w;
    }
    const float4* W4 = (const float4*)W2;
    float4* WS4 = (float4*)WS;
    #pragma unroll
    for (int i = 0; i < 2; ++i) WS4[i * 256 + t] = W4[i * 256 + t];
    __syncthreads();

    int tx = t & 7, ty = t >> 3;        // ch group (0..7), node group (0..31)
    int c4 = tx * 4, n4 = ty * 4;
    float acc[4][4];
    #pragma unroll
    for (int a = 0; a < 4; ++a)
        #pragma unroll
        for (int b = 0; b < 4; ++b) acc[a][b] = 0.f;

    #pragma unroll 8
    for (int k = 0; k < C1; ++k){
        float4 xa = *(const float4*)&XT[k][n4];
        float4 wb = *(const float4*)&WS[k * C2 + c4];
        const float xv[4] = {xa.x, xa.y, xa.z, xa.w};
        const float wv[4] = {wb.x, wb.y, wb.z, wb.w};
        #pragma unroll
        for (int a = 0; a < 4; ++a)
            #pragma unroll
            for (int b = 0; b < 4; ++b)
                acc[a][b] = fmaf(xv[a], wv[b], acc[a][b]);
    }

    #pragma unroll
    for (int a = 0; a < 4; ++a){
        int n = blockIdx.x * 128 + n4 + a;
        if (n < NN){
            float4 o = {acc[a][0], acc[a][1], acc[a][2], acc[a][3]};
            *(float4*)&h2[(size_t)n * C2 + c4] = o;
        }
    }
}

// ---------------- attention coefficients ----------------

__global__ void k_alpha1(const float* __restrict__ h, const float* __restrict__ asrc,
                         const float* __restrict__ adst, float* as, float* ad){
    int i = blockIdx.x * 256 + threadIdx.x;   // node*H1 + head
    if (i >= NN * H1) return;
    int node = i >> 2, hd = i & 3;
    const float* hr = h + (size_t)node * C1 + hd * HID1;
    float sa = 0.f, da = 0.f;
    #pragma unroll
    for (int c = 0; c < HID1; ++c){
        float v = hr[c];
        sa = fmaf(v, asrc[hd * HID1 + c], sa);
        da = fmaf(v, adst[hd * HID1 + c], da);
    }
    as[i] = sa; ad[i] = da;
}

__global__ void k_alpha2(const float* __restrict__ h2, const float* __restrict__ asrc,
                         const float* __restrict__ adst, float* as, float* ad){
    int i = blockIdx.x * 256 + threadIdx.x;   // node
    if (i >= NN) return;
    const float* hr = h2 + (size_t)i * C2;
    float sa = 0.f, da = 0.f;
    #pragma unroll
    for (int c = 0; c < C2; ++c){
        float v = hr[c];
        sa = fmaf(v, asrc[c], sa);
        da = fmaf(v, adst[c], da);
    }
    as[i] = sa; ad[i] = da;
}

// ---------------- aggregation ----------------

// one 64-lane wave per dst node: lane = channel c (head = c>>4)
__global__ void k_agg1(const int* __restrict__ srcs, const int* __restrict__ rows,
                       const int* __restrict__ deg, const float* __restrict__ h,
                       const float* __restrict__ as, const float* __restrict__ ad,
                       const float* __restrict__ b1, float* __restrict__ hp){
    int node = blockIdx.x * 4 + (threadIdx.x >> 6);
    if (node >= NN) return;
    int lane = threadIdx.x & 63;
    int hd = lane >> 4;
    int sub = lane & 15;
    int start = rows[node], dg = deg[node];
    float adv = ad[node * H1 + hd];

    // pass 1: online softmax (16 lanes per head, strided over edges)
    float m = -1e30f, ssum = 0.f;
    for (int j = sub; j < dg; j += 16){
        int s = srcs[start + j];
        float v = lrelu(as[s * H1 + hd] + adv);
        float nm = fmaxf(m, v);
        ssum = ssum * __expf(m - nm) + __expf(v - nm);
        m = nm;
    }
    #pragma unroll
    for (int off = 1; off < 16; off <<= 1){
        float om = __shfl_xor(m, off);
        float os = __shfl_xor(ssum, off);
        float nm = fmaxf(m, om);
        ssum = ssum * __expf(m - nm) + os * __expf(om - nm);
        m = nm;
    }
    float inv = 1.f / (ssum + EPSF);

    // pass 2: gather h[src] (coalesced 256B/edge), 2-edge unroll
    float acc = 0.f;
    int j = 0;
    for (; j + 1 < dg; j += 2){
        int s0 = srcs[start + j], s1 = srcs[start + j + 1];
        float v0 = lrelu(as[s0 * H1 + hd] + adv);
        float v1 = lrelu(as[s1 * H1 + hd] + adv);
        float h0 = h[(size_t)s0 * C1 + lane];
        float hv = h[(size_t)s1 * C1 + lane];
        acc = fmaf(h0, __expf(v0 - m) * inv, acc);
        acc = fmaf(hv, __expf(v1 - m) * inv, acc);
    }
    if (j < dg){
        int s = srcs[start + j];
        float v = lrelu(as[s * H1 + hd] + adv);
        acc = fmaf(h[(size_t)s * C1 + lane], __expf(v - m) * inv, acc);
    }
    float o = acc + b1[lane];
    hp[(size_t)node * C1 + lane] = o > 0.f ? o : expm1f(o);   // fused bias+ELU
}

// two nodes per wave: 32 lanes per node, lane = channel c
__global__ void k_agg2(const int* __restrict__ srcs, const int* __restrict__ rows,
                       const int* __restrict__ deg, const float* __restrict__ h2,
                       const float* __restrict__ as, const float* __restrict__ ad,
                       const float* __restrict__ b2, float* __restrict__ out){
    int node = blockIdx.x * 8 + (threadIdx.x >> 5);
    if (node >= NN) return;
    int lane = threadIdx.x & 31;
    int start = rows[node], dg = deg[node];
    float adv = ad[node];

    float m = -1e30f, ssum = 0.f;
    for (int j = lane; j < dg; j += 32){
        int s = srcs[start + j];
        float v = lrelu(as[s] + adv);
        float nm = fmaxf(m, v);
        ssum = ssum * __expf(m - nm) + __expf(v - nm);
        m = nm;
    }
    #pragma unroll
    for (int off = 1; off < 32; off <<= 1){
        float om = __shfl_xor(m, off);
        float os = __shfl_xor(ssum, off);
        float nm = fmaxf(m, om);
        ssum = ssum * __expf(m - nm) + os * __expf(om - nm);
        m = nm;
    }
    float inv = 1.f / (ssum + EPSF);

    float acc = 0.f;
    int j = 0;
    for (; j + 1 < dg; j += 2){
        int s0 = srcs[start + j], s1 = srcs[start + j + 1];
        float v0 = lrelu(as[s0] + adv);
        float v1 = lrelu(as[s1] + adv);
        float h0 = h2[(size_t)s0 * C2 + lane];
        float hv = h2[(size_t)s1 * C2 + lane];
        acc = fmaf(h0, __expf(v0 - m) * inv, acc);
        acc = fmaf(hv, __expf(v1 - m) * inv, acc);
    }
    if (j < dg){
        int s = srcs[start + j];
        acc = fmaf(h2[(size_t)s * C2 + lane], __expf(lrelu(as[s] + adv) - m) * inv, acc);
    }
    out[(size_t)node * C2 + lane] = acc + b2[lane];
}

extern "C" void kernel_launch(void* const* d_in, const int* in_sizes, int n_in,
                              void* d_out, int out_size, void* d_ws, size_t ws_size,
                              hipStream_t stream) {
    const float* x    = (const float*)d_in[0];
    const int*   ei   = (const int*)  d_in[1];
    const float* W1   = (const float*)d_in[2];
    const float* as1w = (const float*)d_in[3];
    const float* ad1w = (const float*)d_in[4];
    const float* b1   = (const float*)d_in[5];
    const float* W2   = (const float*)d_in[6];
    const float* as2w = (const float*)d_in[7];
    const float* ad2w = (const float*)d_in[8];
    const float* b2   = (const float*)d_in[9];
    float* out = (float*)d_out;

    float* p = (float*)d_ws;
    float* h1   = p; p += (size_t)NN * C1;
    float* hp   = p; p += (size_t)NN * C1;
    float* as1  = p; p += (size_t)NN * H1;
    float* ad1  = p; p += (size_t)NN * H1;
    float* h2   = p; p += (size_t)NN * C2;
    float* as2  = p; p += NN;
    float* ad2  = p; p += NN;
    int* deg  = (int*)p; p += NN;
    int* rows = (int*)p; p += NN;
    int* cur  = (int*)p; p += NN;
    int* srcs = (int*)p; p += NE;
    int* bsum = (int*)p; p += 256;

    dim3 B(256);
    // CSR build
    k_zero  <<<NB, B, 0, stream>>>(deg);
    k_deg   <<<(NE + 255) / 256, B, 0, stream>>>(ei, deg);
    k_scanA <<<NB, B, 0, stream>>>(deg, rows, bsum);
    k_scanB <<<1, B, 0, stream>>>(bsum);
    k_scanC <<<NB, B, 0, stream>>>(rows, bsum, cur);
    k_bucket<<<(NE + 255) / 256, B, 0, stream>>>(ei, cur, srcs);
    // layer 1
    k_gemm1 <<<(NN + 63) / 64, B, 0, stream>>>(x, W1, h1);
    k_alpha1<<<(NN * H1 + 255) / 256, B, 0, stream>>>(h1, as1w, ad1w, as1, ad1);
    k_agg1  <<<(NN + 3) / 4, B, 0, stream>>>(srcs, rows, deg, h1, as1, ad1, b1, hp);
    // layer 2
    k_gemm2 <<<(NN + 127) / 128, B, 0, stream>>>(hp, W2, h2);
    k_alpha2<<<(NN + 255) / 256, B, 0, stream>>>(h2, as2w, ad2w, as2, ad2);
    k_agg2  <<<(NN + 7) / 8, B, 0, stream>>>(srcs, rows, deg, h2, as2, ad2, b2, out);
}

// Round 4
// 275.709 us; speedup vs baseline: 2.3472x; 1.1270x over previous
//
#include <hip/hip_runtime.h>
#include <math.h>

#define NN 50000
#define NE 800000
#define INCH 128
#define HID1 16
#define H1 4
#define C1 64      /* HEADS*HID */
#define C2 32
#define NEG 0.2f
#define EPSF 1e-16f
#define NB 196     /* ceil(NN/256) */
#define CAP 128    /* per-node staged-edge cap; deg ~ Poisson(16), max ~45 */

static __device__ __forceinline__ float lrelu(float v){ return v > 0.f ? v : NEG * v; }

// ---------------- CSR build (dst-sorted) ----------------

__global__ void k_deg(const int* __restrict__ ei, int* deg){
    int e = blockIdx.x * 256 + threadIdx.x;
    if (e < NE) atomicAdd(&deg[ei[NE + e]], 1);
}

__global__ void k_scanA(const int* __restrict__ deg, int* rows, int* bsum){
    __shared__ int sh[256];
    int i = blockIdx.x * 256 + threadIdx.x;
    int v = (i < NN) ? deg[i] : 0;
    sh[threadIdx.x] = v;
    __syncthreads();
    int val = v;
    for (int off = 1; off < 256; off <<= 1){
        int t = (threadIdx.x >= off) ? sh[threadIdx.x - off] : 0;
        __syncthreads();
        val += t;
        sh[threadIdx.x] = val;
        __syncthreads();
    }
    if (i < NN) rows[i] = val - v;                 // exclusive
    if (threadIdx.x == 255) bsum[blockIdx.x] = val; // block total
}

__global__ void k_scanB(int* bsum){
    __shared__ int sh[256];
    int v = (threadIdx.x < NB) ? bsum[threadIdx.x] : 0;
    sh[threadIdx.x] = v;
    __syncthreads();
    int val = v;
    for (int off = 1; off < 256; off <<= 1){
        int t = (threadIdx.x >= off) ? sh[threadIdx.x - off] : 0;
        __syncthreads();
        val += t;
        sh[threadIdx.x] = val;
        __syncthreads();
    }
    if (threadIdx.x < NB) bsum[threadIdx.x] = val - v; // exclusive
}

__global__ void k_scanC(int* rows, const int* __restrict__ bsum, int* cur){
    int i = blockIdx.x * 256 + threadIdx.x;
    if (i < NN){
        int r = rows[i] + bsum[blockIdx.x];
        rows[i] = r;
        cur[i] = r;
    }
}

__global__ void k_bucket(const int* __restrict__ ei, int* cur, int* srcs){
    int e = blockIdx.x * 256 + threadIdx.x;
    if (e >= NE) return;
    int d = ei[NE + e];
    int pos = atomicAdd(&cur[d], 1);
    srcs[pos] = ei[e];
}

// ---- GEMM 1: [NN,128]x[128,64], 64x64 tile, fused alpha1 epilogue ----

__global__ void k_gemm1(const float* __restrict__ x, const float* __restrict__ W,
                        const float* __restrict__ asrc, const float* __restrict__ adst,
                        float* __restrict__ h, float* __restrict__ as1, float* __restrict__ ad1){
    __shared__ float XT[INCH][68];
    __shared__ float WS[INCH * C1];
    __shared__ float ps[64][17];
    __shared__ float pd[64][17];

    int t = threadIdx.x;
    int nodeL = t >> 2;
    int kc = t & 3;
    int g = blockIdx.x * 64 + nodeL;
    int gc = min(g, NN - 1);
    const float4* xr = (const float4*)(x + (size_t)gc * INCH);
    #pragma unroll
    for (int i = 0; i < 8; ++i){
        int k = kc * 32 + i * 4;
        float4 v = xr[k >> 2];
        XT[k + 0][nodeL] = v.x;
        XT[k + 1][nodeL] = v.y;
        XT[k + 2][nodeL] = v.z;
        XT[k + 3][nodeL] = v.w;
    }
    const float4* W4 = (const float4*)W;
    float4* WS4 = (float4*)WS;
    #pragma unroll
    for (int i = 0; i < 8; ++i) WS4[i * 256 + t] = W4[i * 256 + t];
    __syncthreads();

    int tx = t & 15, ty = t >> 4;
    int c4 = tx * 4, n4 = ty * 4;
    float acc[4][4];
    #pragma unroll
    for (int a = 0; a < 4; ++a)
        #pragma unroll
        for (int b = 0; b < 4; ++b) acc[a][b] = 0.f;

    #pragma unroll 8
    for (int k = 0; k < INCH; ++k){
        float4 xa = *(const float4*)&XT[k][n4];
        float4 wb = *(const float4*)&WS[k * C1 + c4];
        const float xv[4] = {xa.x, xa.y, xa.z, xa.w};
        const float wv[4] = {wb.x, wb.y, wb.z, wb.w};
        #pragma unroll
        for (int a = 0; a < 4; ++a)
            #pragma unroll
            for (int b = 0; b < 4; ++b)
                acc[a][b] = fmaf(xv[a], wv[b], acc[a][b]);
    }

    // store h + alpha partials (this thread's 4 ch are within one head)
    int hd = tx >> 2;
    #pragma unroll
    for (int a = 0; a < 4; ++a){
        int n = blockIdx.x * 64 + n4 + a;
        if (n < NN){
            float4 o = {acc[a][0], acc[a][1], acc[a][2], acc[a][3]};
            *(float4*)&h[(size_t)n * C1 + c4] = o;
        }
        float sa = 0.f, da = 0.f;
        #pragma unroll
        for (int b = 0; b < 4; ++b){
            float wsv = asrc[hd * HID1 + (c4 & 15) + b];
            float wdv = adst[hd * HID1 + (c4 & 15) + b];
            sa = fmaf(acc[a][b], wsv, sa);
            da = fmaf(acc[a][b], wdv, da);
        }
        ps[n4 + a][tx] = sa;
        pd[n4 + a][tx] = da;
    }
    __syncthreads();
    int nd = t & 63, hh = t >> 6;
    int g2 = blockIdx.x * 64 + nd;
    if (g2 < NN){
        float sa = ps[nd][hh*4+0] + ps[nd][hh*4+1] + ps[nd][hh*4+2] + ps[nd][hh*4+3];
        float da = pd[nd][hh*4+0] + pd[nd][hh*4+1] + pd[nd][hh*4+2] + pd[nd][hh*4+3];
        as1[g2 * H1 + hh] = sa;
        ad1[g2 * H1 + hh] = da;
    }
}

// ---- GEMM 2: [NN,64]x[64,32], 128x32 tile, fused alpha2 epilogue ----

__global__ void k_gemm2(const float* __restrict__ hp, const float* __restrict__ W2,
                        const float* __restrict__ asrc, const float* __restrict__ adst,
                        float* __restrict__ h2, float* __restrict__ as2, float* __restrict__ ad2){
    __shared__ float XT[C1][132];
    __shared__ float WS[C1 * C2];
    __shared__ float ps[128][9];
    __shared__ float pd[128][9];

    int t = threadIdx.x;
    int nodeL = t >> 1;
    int kc = t & 1;
    int g = blockIdx.x * 128 + nodeL;
    int gc = min(g, NN - 1);
    const float4* xr = (const float4*)(hp + (size_t)gc * C1);
    #pragma unroll
    for (int i = 0; i < 8; ++i){
        int k = kc * 32 + i * 4;
        float4 v = xr[k >> 2];
        XT[k + 0][nodeL] = v.x;
        XT[k + 1][nodeL] = v.y;
        XT[k + 2][nodeL] = v.z;
        XT[k + 3][nodeL] = v.w;
    }
    const float4* W4 = (const float4*)W2;
    float4* WS4 = (float4*)WS;
    #pragma unroll
    for (int i = 0; i < 2; ++i) WS4[i * 256 + t] = W4[i * 256 + t];
    __syncthreads();

    int tx = t & 7, ty = t >> 3;
    int c4 = tx * 4, n4 = ty * 4;
    float acc[4][4];
    #pragma unroll
    for (int a = 0; a < 4; ++a)
        #pragma unroll
        for (int b = 0; b < 4; ++b) acc[a][b] = 0.f;

    #pragma unroll 8
    for (int k = 0; k < C1; ++k){
        float4 xa = *(const float4*)&XT[k][n4];
        float4 wb = *(const float4*)&WS[k * C2 + c4];
        const float xv[4] = {xa.x, xa.y, xa.z, xa.w};
        const float wv[4] = {wb.x, wb.y, wb.z, wb.w};
        #pragma unroll
        for (int a = 0; a < 4; ++a)
            #pragma unroll
            for (int b = 0; b < 4; ++b)
                acc[a][b] = fmaf(xv[a], wv[b], acc[a][b]);
    }

    #pragma unroll
    for (int a = 0; a < 4; ++a){
        int n = blockIdx.x * 128 + n4 + a;
        if (n < NN){
            float4 o = {acc[a][0], acc[a][1], acc[a][2], acc[a][3]};
            *(float4*)&h2[(size_t)n * C2 + c4] = o;
        }
        float sa = 0.f, da = 0.f;
        #pragma unroll
        for (int b = 0; b < 4; ++b){
            sa = fmaf(acc[a][b], asrc[c4 + b], sa);
            da = fmaf(acc[a][b], adst[c4 + b], da);
        }
        ps[n4 + a][tx] = sa;
        pd[n4 + a][tx] = da;
    }
    __syncthreads();
    if (t < 128){
        int n = blockIdx.x * 128 + t;
        if (n < NN){
            float sa = 0.f, da = 0.f;
            #pragma unroll
            for (int i = 0; i < 8; ++i){ sa += ps[t][i]; da += pd[t][i]; }
            as2[n] = sa;
            ad2[n] = da;
        }
    }
}

// ---------------- aggregation (3-phase, LDS-staged weights) ----------------

// one wave per node; lane = channel; grid = NN/4 exactly (50000 % 4 == 0)
__global__ __launch_bounds__(256) void k_agg1(
        const int* __restrict__ srcs, const int* __restrict__ rows,
        const int* __restrict__ deg, const float* __restrict__ h,
        const float* __restrict__ as, const float* __restrict__ ad,
        const float* __restrict__ b1, float* __restrict__ hp){
    __shared__ float vbuf[4][CAP * H1];
    __shared__ int   sbuf[4][CAP];
    __shared__ float minv[4][8];
    int wv = threadIdx.x >> 6;
    int lane = threadIdx.x & 63;
    int node = blockIdx.x * 4 + wv;
    int hd = lane >> 4, sub = lane & 15;
    int start = rows[node], dg = deg[node];
    float adv = ad[node * H1 + hd];
    bool fits = (dg <= CAP);

    // phase 1: online softmax + stage v, src
    float m = -1e30f, ssum = 0.f;
    for (int j = sub; j < dg; j += 16){
        int s = srcs[start + j];
        float v = lrelu(as[s * H1 + hd] + adv);
        if (fits){
            vbuf[wv][j * H1 + hd] = v;
            if (hd == 0) sbuf[wv][j] = s;
        }
        float nm = fmaxf(m, v);
        ssum = ssum * __expf(m - nm) + __expf(v - nm);
        m = nm;
    }
    #pragma unroll
    for (int off = 1; off < 16; off <<= 1){
        float om = __shfl_xor(m, off);
        float os = __shfl_xor(ssum, off);
        float nm = fmaxf(m, om);
        ssum = ssum * __expf(m - nm) + os * __expf(om - nm);
        m = nm;
    }
    float inv = 1.f / (ssum + EPSF);
    if (sub == 0){ minv[wv][hd] = m; minv[wv][4 + hd] = inv; }
    __syncthreads();

    // phase 2: v -> weight, edge*head items distributed over 64 lanes
    if (fits){
        int tot = dg * H1;
        for (int it = lane; it < tot; it += 64){
            int th = it & 3;
            vbuf[wv][it] = __expf(vbuf[wv][it] - minv[wv][th]) * minv[wv][4 + th];
        }
    }
    __syncthreads();

    // phase 3: pure gather + FMA
    float acc0 = 0.f, acc1 = 0.f;
    const float* hL = h + lane;
    if (fits){
        int j = 0;
        for (; j + 3 < dg; j += 4){
            int s0 = sbuf[wv][j], s1 = sbuf[wv][j+1], s2 = sbuf[wv][j+2], s3 = sbuf[wv][j+3];
            float w0 = vbuf[wv][(j+0)*H1+hd], w1 = vbuf[wv][(j+1)*H1+hd];
            float w2 = vbuf[wv][(j+2)*H1+hd], w3 = vbuf[wv][(j+3)*H1+hd];
            float g0 = hL[(size_t)s0 * C1], g1 = hL[(size_t)s1 * C1];
            float g2 = hL[(size_t)s2 * C1], g3 = hL[(size_t)s3 * C1];
            acc0 = fmaf(g0, w0, acc0);
            acc1 = fmaf(g1, w1, acc1);
            acc0 = fmaf(g2, w2, acc0);
            acc1 = fmaf(g3, w3, acc1);
        }
        for (; j < dg; ++j)
            acc0 = fmaf(hL[(size_t)sbuf[wv][j] * C1], vbuf[wv][j*H1+hd], acc0);
    } else {
        for (int j = 0; j < dg; ++j){
            int s = srcs[start + j];
            float v = lrelu(as[s * H1 + hd] + adv);
            acc0 = fmaf(hL[(size_t)s * C1], __expf(v - m) * inv, acc0);
        }
    }
    float o = acc0 + acc1 + b1[lane];
    hp[(size_t)node * C1 + lane] = o > 0.f ? o : expm1f(o);
}

// two nodes per wave; 32 lanes per node; grid = NN/8 exactly (50000 % 8 == 0)
__global__ __launch_bounds__(256) void k_agg2(
        const int* __restrict__ srcs, const int* __restrict__ rows,
        const int* __restrict__ deg, const float* __restrict__ h2,
        const float* __restrict__ as, const float* __restrict__ ad,
        const float* __restrict__ b2, float* __restrict__ out){
    __shared__ float vbuf[8][CAP];
    __shared__ int   sbuf[8][CAP];
    int sl = threadIdx.x >> 5;
    int lane = threadIdx.x & 31;
    int node = blockIdx.x * 8 + sl;
    int start = rows[node], dg = deg[node];
    float adv = ad[node];
    bool fits = (dg <= CAP);

    float m = -1e30f, ssum = 0.f;
    for (int j = lane; j < dg; j += 32){
        int s = srcs[start + j];
        float v = lrelu(as[s] + adv);
        if (fits){ vbuf[sl][j] = v; sbuf[sl][j] = s; }
        float nm = fmaxf(m, v);
        ssum = ssum * __expf(m - nm) + __expf(v - nm);
        m = nm;
    }
    #pragma unroll
    for (int off = 1; off < 32; off <<= 1){
        float om = __shfl_xor(m, off);
        float os = __shfl_xor(ssum, off);
        float nm = fmaxf(m, om);
        ssum = ssum * __expf(m - nm) + os * __expf(om - nm);
        m = nm;
    }
    float inv = 1.f / (ssum + EPSF);
    if (fits)
        for (int j = lane; j < dg; j += 32)
            vbuf[sl][j] = __expf(vbuf[sl][j] - m) * inv;   // same-lane rewrite
    __syncthreads();

    float acc0 = 0.f, acc1 = 0.f;
    const float* hL = h2 + lane;
    if (fits){
        int j = 0;
        for (; j + 3 < dg; j += 4){
            int s0 = sbuf[sl][j], s1 = sbuf[sl][j+1], s2 = sbuf[sl][j+2], s3 = sbuf[sl][j+3];
            float w0 = vbuf[sl][j], w1 = vbuf[sl][j+1], w2 = vbuf[sl][j+2], w3 = vbuf[sl][j+3];
            float g0 = hL[(size_t)s0 * C2], g1 = hL[(size_t)s1 * C2];
            float g2 = hL[(size_t)s2 * C2], g3 = hL[(size_t)s3 * C2];
            acc0 = fmaf(g0, w0, acc0);
            acc1 = fmaf(g1, w1, acc1);
            acc0 = fmaf(g2, w2, acc0);
            acc1 = fmaf(g3, w3, acc1);
        }
        for (; j < dg; ++j)
            acc0 = fmaf(hL[(size_t)sbuf[sl][j] * C2], vbuf[sl][j], acc0);
    } else {
        for (int j = 0; j < dg; ++j){
            int s = srcs[start + j];
            acc0 = fmaf(hL[(size_t)s * C2], __expf(lrelu(as[s] + adv) - m) * inv, acc0);
        }
    }
    out[(size_t)node * C2 + lane] = acc0 + acc1 + b2[lane];
}

extern "C" void kernel_launch(void* const* d_in, const int* in_sizes, int n_in,
                              void* d_out, int out_size, void* d_ws, size_t ws_size,
                              hipStream_t stream) {
    const float* x    = (const float*)d_in[0];
    const int*   ei   = (const int*)  d_in[1];
    const float* W1   = (const float*)d_in[2];
    const float* as1w = (const float*)d_in[3];
    const float* ad1w = (const float*)d_in[4];
    const float* b1   = (const float*)d_in[5];
    const float* W2   = (const float*)d_in[6];
    const float* as2w = (const float*)d_in[7];
    const float* ad2w = (const float*)d_in[8];
    const float* b2   = (const float*)d_in[9];
    float* out = (float*)d_out;

    float* p = (float*)d_ws;
    float* h1   = p; p += (size_t)NN * C1;
    float* hp   = p; p += (size_t)NN * C1;
    float* as1  = p; p += (size_t)NN * H1;
    float* ad1  = p; p += (size_t)NN * H1;
    float* h2   = p; p += (size_t)NN * C2;
    float* as2  = p; p += NN;
    float* ad2  = p; p += NN;
    int* deg  = (int*)p; p += NN;
    int* rows = (int*)p; p += NN;
    int* cur  = (int*)p; p += NN;
    int* srcs = (int*)p; p += NE;
    int* bsum = (int*)p; p += 256;

    dim3 B(256);
    // CSR build
    hipMemsetAsync(deg, 0, NN * sizeof(int), stream);
    k_deg   <<<(NE + 255) / 256, B, 0, stream>>>(ei, deg);
    k_scanA <<<NB, B, 0, stream>>>(deg, rows, bsum);
    k_scanB <<<1, B, 0, stream>>>(bsum);
    k_scanC <<<NB, B, 0, stream>>>(rows, bsum, cur);
    k_bucket<<<(NE + 255) / 256, B, 0, stream>>>(ei, cur, srcs);
    // layer 1
    k_gemm1 <<<(NN + 63) / 64, B, 0, stream>>>(x, W1, as1w, ad1w, h1, as1, ad1);
    k_agg1  <<<NN / 4, B, 0, stream>>>(srcs, rows, deg, h1, as1, ad1, b1, hp);
    // layer 2
    k_gemm2 <<<(NN + 127) / 128, B, 0, stream>>>(hp, W2, as2w, ad2w, h2, as2, ad2);
    k_agg2  <<<NN / 8, B, 0, stream>>>(srcs, rows, deg, h2, as2, ad2, b2, out);
}

// Round 5
// 245.911 us; speedup vs baseline: 2.6316x; 1.1212x over previous
//
#include <hip/hip_runtime.h>
#include <math.h>

#define NN 50000
#define NE 800000
#define INCH 128
#define HID1 16
#define H1 4
#define C1 64      /* HEADS*HID */
#define C2 32
#define NEG 0.2f
#define EPSF 1e-16f
#define NB 196     /* ceil(NN/256) */
#define CAP 128    /* per-node staged-edge cap; deg ~ Poisson(16) */
#define BSH 7      /* 128 nodes per coarse bucket */
#define NBKT 391   /* ceil(NN/128) */
#define EPB 2048   /* edges per k_part1 block */
#define NPB1 391   /* ceil(NE/EPB) */

static __device__ __forceinline__ float lrelu(float v){ return v > 0.f ? v : NEG * v; }

// ---------------- CSR build (dst-sorted, 2-level counting sort) ----------------

__global__ void k_deg(const int* __restrict__ ei, int* deg){
    int e = blockIdx.x * 256 + threadIdx.x;
    if (e < NE) atomicAdd(&deg[ei[NE + e]], 1);
}

__global__ void k_scanA(const int* __restrict__ deg, int* rows, int* bsum){
    __shared__ int sh[256];
    int i = blockIdx.x * 256 + threadIdx.x;
    int v = (i < NN) ? deg[i] : 0;
    sh[threadIdx.x] = v;
    __syncthreads();
    int val = v;
    for (int off = 1; off < 256; off <<= 1){
        int t = (threadIdx.x >= off) ? sh[threadIdx.x - off] : 0;
        __syncthreads();
        val += t;
        sh[threadIdx.x] = val;
        __syncthreads();
    }
    if (i < NN) rows[i] = val - v;                 // exclusive
    if (threadIdx.x == 255) bsum[blockIdx.x] = val; // block total
}

__global__ void k_scanB(int* bsum){
    __shared__ int sh[256];
    int v = (threadIdx.x < NB) ? bsum[threadIdx.x] : 0;
    sh[threadIdx.x] = v;
    __syncthreads();
    int val = v;
    for (int off = 1; off < 256; off <<= 1){
        int t = (threadIdx.x >= off) ? sh[threadIdx.x - off] : 0;
        __syncthreads();
        val += t;
        sh[threadIdx.x] = val;
        __syncthreads();
    }
    if (threadIdx.x < NB) bsum[threadIdx.x] = val - v; // exclusive
}

__global__ void k_scanC(int* rows, const int* __restrict__ bsum){
    int i = blockIdx.x * 256 + threadIdx.x;
    if (i < NN) rows[i] += bsum[blockIdx.x];
}

__global__ void k_binit(const int* __restrict__ rows, int* bcur){
    int b = blockIdx.x * 256 + threadIdx.x;
    if (b < NBKT) bcur[b] = rows[b << BSH];
}

// coarse partition: group edges by bucket per block, one global atomic per (block,bucket)
__global__ __launch_bounds__(256) void k_part1(const int* __restrict__ ei, int* bcur,
                                               int2* __restrict__ pairs){
    __shared__ int hist[512];
    __shared__ int scn[512];
    __shared__ int spos[512];
    __shared__ int gbase[NBKT];
    __shared__ int2 stg[EPB];
    int t = threadIdx.x;
    hist[t] = 0; hist[t + 256] = 0;
    __syncthreads();

    int e0 = blockIdx.x * EPB;
    int tot = NE - e0; if (tot > EPB) tot = EPB;
    int srcv[8], dstv[8], rnk[8], bkt[8];
    #pragma unroll
    for (int k = 0; k < 8; ++k){
        int idx = k * 256 + t;
        if (idx < tot){
            int e = e0 + idx;
            srcv[k] = ei[e];
            dstv[k] = ei[NE + e];
            bkt[k] = dstv[k] >> BSH;
            rnk[k] = atomicAdd(&hist[bkt[k]], 1);
        } else bkt[k] = -1;
    }
    __syncthreads();

    // inclusive scan over 512 slots (ping-pong)
    int* sA = hist; int* sB = scn;
    for (int off = 1; off < 512; off <<= 1){
        int v0 = sA[t]       + ((t       >= off) ? sA[t - off]       : 0);
        int v1 = sA[t + 256] + ((t + 256 >= off) ? sA[t + 256 - off] : 0);
        __syncthreads();
        sB[t] = v0; sB[t + 256] = v1;
        __syncthreads();
        int* tmp = sA; sA = sB; sB = tmp;
    }
    for (int b = t; b < NBKT; b += 256){
        int incl = sA[b];
        int excl = (b > 0) ? sA[b - 1] : 0;
        spos[b] = excl;
        int cnt = incl - excl;
        gbase[b] = (cnt > 0) ? atomicAdd(&bcur[b], cnt) : 0;
    }
    __syncthreads();

    #pragma unroll
    for (int k = 0; k < 8; ++k)
        if (bkt[k] >= 0){
            int2 pr; pr.x = srcv[k]; pr.y = dstv[k];
            stg[spos[bkt[k]] + rnk[k]] = pr;
        }
    __syncthreads();

    for (int i = t; i < tot; i += 256){
        int2 pr = stg[i];
        int b = pr.y >> BSH;
        pairs[gbase[b] + i - spos[b]] = pr;
    }
}

// fine scatter within each bucket: LDS cursors, writes confined to ~8KB region
__global__ __launch_bounds__(256) void k_part2(const int2* __restrict__ pairs,
                                               const int* __restrict__ rows,
                                               int* __restrict__ srcs){
    __shared__ int cur[128];
    int b = blockIdx.x;
    int n0 = b << BSH;
    int t = threadIdx.x;
    if (t < 128){
        int n = n0 + t;
        cur[t] = (n < NN) ? rows[n] : 0;
    }
    __syncthreads();
    int e0 = rows[n0];
    int e1 = (n0 + 128 < NN) ? rows[n0 + 128] : NE;
    for (int i = e0 + t; i < e1; i += 256){
        int2 pr = pairs[i];
        int p = atomicAdd(&cur[pr.y - n0], 1);
        srcs[p] = pr.x;
    }
}

// ---- GEMM 1: [NN,128]x[128,64], 64x64 tile, fused alpha1 epilogue ----

__global__ void k_gemm1(const float* __restrict__ x, const float* __restrict__ W,
                        const float* __restrict__ asrc, const float* __restrict__ adst,
                        float* __restrict__ h, float* __restrict__ as1, float* __restrict__ ad1){
    __shared__ float XT[INCH][68];
    __shared__ float WS[INCH * C1];
    __shared__ float ps[64][17];
    __shared__ float pd[64][17];

    int t = threadIdx.x;
    int nodeL = t >> 2;
    int kc = t & 3;
    int g = blockIdx.x * 64 + nodeL;
    int gc = min(g, NN - 1);
    const float4* xr = (const float4*)(x + (size_t)gc * INCH);
    #pragma unroll
    for (int i = 0; i < 8; ++i){
        int k = kc * 32 + i * 4;
        float4 v = xr[k >> 2];
        XT[k + 0][nodeL] = v.x;
        XT[k + 1][nodeL] = v.y;
        XT[k + 2][nodeL] = v.z;
        XT[k + 3][nodeL] = v.w;
    }
    const float4* W4 = (const float4*)W;
    float4* WS4 = (float4*)WS;
    #pragma unroll
    for (int i = 0; i < 8; ++i) WS4[i * 256 + t] = W4[i * 256 + t];
    __syncthreads();

    int tx = t & 15, ty = t >> 4;
    int c4 = tx * 4, n4 = ty * 4;
    float acc[4][4];
    #pragma unroll
    for (int a = 0; a < 4; ++a)
        #pragma unroll
        for (int b = 0; b < 4; ++b) acc[a][b] = 0.f;

    #pragma unroll 8
    for (int k = 0; k < INCH; ++k){
        float4 xa = *(const float4*)&XT[k][n4];
        float4 wb = *(const float4*)&WS[k * C1 + c4];
        const float xv[4] = {xa.x, xa.y, xa.z, xa.w};
        const float wv[4] = {wb.x, wb.y, wb.z, wb.w};
        #pragma unroll
        for (int a = 0; a < 4; ++a)
            #pragma unroll
            for (int b = 0; b < 4; ++b)
                acc[a][b] = fmaf(xv[a], wv[b], acc[a][b]);
    }

    int hd = tx >> 2;
    #pragma unroll
    for (int a = 0; a < 4; ++a){
        int n = blockIdx.x * 64 + n4 + a;
        if (n < NN){
            float4 o = {acc[a][0], acc[a][1], acc[a][2], acc[a][3]};
            *(float4*)&h[(size_t)n * C1 + c4] = o;
        }
        float sa = 0.f, da = 0.f;
        #pragma unroll
        for (int b = 0; b < 4; ++b){
            float wsv = asrc[hd * HID1 + (c4 & 15) + b];
            float wdv = adst[hd * HID1 + (c4 & 15) + b];
            sa = fmaf(acc[a][b], wsv, sa);
            da = fmaf(acc[a][b], wdv, da);
        }
        ps[n4 + a][tx] = sa;
        pd[n4 + a][tx] = da;
    }
    __syncthreads();
    int nd = t & 63, hh = t >> 6;
    int g2 = blockIdx.x * 64 + nd;
    if (g2 < NN){
        float sa = ps[nd][hh*4+0] + ps[nd][hh*4+1] + ps[nd][hh*4+2] + ps[nd][hh*4+3];
        float da = pd[nd][hh*4+0] + pd[nd][hh*4+1] + pd[nd][hh*4+2] + pd[nd][hh*4+3];
        as1[g2 * H1 + hh] = sa;
        ad1[g2 * H1 + hh] = da;
    }
}

// ---- GEMM 2: [NN,64]x[64,32], 128x32 tile, fused alpha2 epilogue ----

__global__ void k_gemm2(const float* __restrict__ hp, const float* __restrict__ W2,
                        const float* __restrict__ asrc, const float* __restrict__ adst,
                        float* __restrict__ h2, float* __restrict__ as2, float* __restrict__ ad2){
    __shared__ float XT[C1][132];
    __shared__ float WS[C1 * C2];
    __shared__ float ps[128][9];
    __shared__ float pd[128][9];

    int t = threadIdx.x;
    int nodeL = t >> 1;
    int kc = t & 1;
    int g = blockIdx.x * 128 + nodeL;
    int gc = min(g, NN - 1);
    const float4* xr = (const float4*)(hp + (size_t)gc * C1);
    #pragma unroll
    for (int i = 0; i < 8; ++i){
        int k = kc * 32 + i * 4;
        float4 v = xr[k >> 2];
        XT[k + 0][nodeL] = v.x;
        XT[k + 1][nodeL] = v.y;
        XT[k + 2][nodeL] = v.z;
        XT[k + 3][nodeL] = v.w;
    }
    const float4* W4 = (const float4*)W2;
    float4* WS4 = (float4*)WS;
    #pragma unroll
    for (int i = 0; i < 2; ++i) WS4[i * 256 + t] = W4[i * 256 + t];
    __syncthreads();

    int tx = t & 7, ty = t >> 3;
    int c4 = tx * 4, n4 = ty * 4;
    float acc[4][4];
    #pragma unroll
    for (int a = 0; a < 4; ++a)
        #pragma unroll
        for (int b = 0; b < 4; ++b) acc[a][b] = 0.f;

    #pragma unroll 8
    for (int k = 0; k < C1; ++k){
        float4 xa = *(const float4*)&XT[k][n4];
        float4 wb = *(const float4*)&WS[k * C2 + c4];
        const float xv[4] = {xa.x, xa.y, xa.z, xa.w};
        const float wv[4] = {wb.x, wb.y, wb.z, wb.w};
        #pragma unroll
        for (int a = 0; a < 4; ++a)
            #pragma unroll
            for (int b = 0; b < 4; ++b)
                acc[a][b] = fmaf(xv[a], wv[b], acc[a][b]);
    }

    #pragma unroll
    for (int a = 0; a < 4; ++a){
        int n = blockIdx.x * 128 + n4 + a;
        if (n < NN){
            float4 o = {acc[a][0], acc[a][1], acc[a][2], acc[a][3]};
            *(float4*)&h2[(size_t)n * C2 + c4] = o;
        }
        float sa = 0.f, da = 0.f;
        #pragma unroll
        for (int b = 0; b < 4; ++b){
            sa = fmaf(acc[a][b], asrc[c4 + b], sa);
            da = fmaf(acc[a][b], adst[c4 + b], da);
        }
        ps[n4 + a][tx] = sa;
        pd[n4 + a][tx] = da;
    }
    __syncthreads();
    if (t < 128){
        int n = blockIdx.x * 128 + t;
        if (n < NN){
            float sa = 0.f, da = 0.f;
            #pragma unroll
            for (int i = 0; i < 8; ++i){ sa += ps[t][i]; da += pd[t][i]; }
            as2[n] = sa;
            ad2[n] = da;
        }
    }
}

// ---------------- aggregation (3-phase, LDS-staged weights) ----------------

__global__ __launch_bounds__(256) void k_agg1(
        const int* __restrict__ srcs, const int* __restrict__ rows,
        const int* __restrict__ deg, const float* __restrict__ h,
        const float* __restrict__ as, const float* __restrict__ ad,
        const float* __restrict__ b1, float* __restrict__ hp){
    __shared__ float vbuf[4][CAP * H1];
    __shared__ int   sbuf[4][CAP];
    __shared__ float minv[4][8];
    int wv = threadIdx.x >> 6;
    int lane = threadIdx.x & 63;
    int node = blockIdx.x * 4 + wv;
    int hd = lane >> 4, sub = lane & 15;
    int start = rows[node], dg = deg[node];
    float adv = ad[node * H1 + hd];
    bool fits = (dg <= CAP);

    float m = -1e30f, ssum = 0.f;
    for (int j = sub; j < dg; j += 16){
        int s = srcs[start + j];
        float v = lrelu(as[s * H1 + hd] + adv);
        if (fits){
            vbuf[wv][j * H1 + hd] = v;
            if (hd == 0) sbuf[wv][j] = s;
        }
        float nm = fmaxf(m, v);
        ssum = ssum * __expf(m - nm) + __expf(v - nm);
        m = nm;
    }
    #pragma unroll
    for (int off = 1; off < 16; off <<= 1){
        float om = __shfl_xor(m, off);
        float os = __shfl_xor(ssum, off);
        float nm = fmaxf(m, om);
        ssum = ssum * __expf(m - nm) + os * __expf(om - nm);
        m = nm;
    }
    float inv = 1.f / (ssum + EPSF);
    if (sub == 0){ minv[wv][hd] = m; minv[wv][4 + hd] = inv; }
    __syncthreads();

    if (fits){
        int tot = dg * H1;
        for (int it = lane; it < tot; it += 64){
            int th = it & 3;
            vbuf[wv][it] = __expf(vbuf[wv][it] - minv[wv][th]) * minv[wv][4 + th];
        }
    }
    __syncthreads();

    float acc0 = 0.f, acc1 = 0.f;
    const float* hL = h + lane;
    if (fits){
        int j = 0;
        for (; j + 3 < dg; j += 4){
            int s0 = sbuf[wv][j], s1 = sbuf[wv][j+1], s2 = sbuf[wv][j+2], s3 = sbuf[wv][j+3];
            float w0 = vbuf[wv][(j+0)*H1+hd], w1 = vbuf[wv][(j+1)*H1+hd];
            float w2 = vbuf[wv][(j+2)*H1+hd], w3 = vbuf[wv][(j+3)*H1+hd];
            float g0 = hL[(size_t)s0 * C1], g1 = hL[(size_t)s1 * C1];
            float g2 = hL[(size_t)s2 * C1], g3 = hL[(size_t)s3 * C1];
            acc0 = fmaf(g0, w0, acc0);
            acc1 = fmaf(g1, w1, acc1);
            acc0 = fmaf(g2, w2, acc0);
            acc1 = fmaf(g3, w3, acc1);
        }
        for (; j < dg; ++j)
            acc0 = fmaf(hL[(size_t)sbuf[wv][j] * C1], vbuf[wv][j*H1+hd], acc0);
    } else {
        for (int j = 0; j < dg; ++j){
            int s = srcs[start + j];
            float v = lrelu(as[s * H1 + hd] + adv);
            acc0 = fmaf(hL[(size_t)s * C1], __expf(v - m) * inv, acc0);
        }
    }
    float o = acc0 + acc1 + b1[lane];
    hp[(size_t)node * C1 + lane] = o > 0.f ? o : expm1f(o);
}

__global__ __launch_bounds__(256) void k_agg2(
        const int* __restrict__ srcs, const int* __restrict__ rows,
        const int* __restrict__ deg, const float* __restrict__ h2,
        const float* __restrict__ as, const float* __restrict__ ad,
        const float* __restrict__ b2, float* __restrict__ out){
    __shared__ float vbuf[8][CAP];
    __shared__ int   sbuf[8][CAP];
    int sl = threadIdx.x >> 5;
    int lane = threadIdx.x & 31;
    int node = blockIdx.x * 8 + sl;
    int start = rows[node], dg = deg[node];
    float adv = ad[node];
    bool fits = (dg <= CAP);

    float m = -1e30f, ssum = 0.f;
    for (int j = lane; j < dg; j += 32){
        int s = srcs[start + j];
        float v = lrelu(as[s] + adv);
        if (fits){ vbuf[sl][j] = v; sbuf[sl][j] = s; }
        float nm = fmaxf(m, v);
        ssum = ssum * __expf(m - nm) + __expf(v - nm);
        m = nm;
    }
    #pragma unroll
    for (int off = 1; off < 32; off <<= 1){
        float om = __shfl_xor(m, off);
        float os = __shfl_xor(ssum, off);
        float nm = fmaxf(m, om);
        ssum = ssum * __expf(m - nm) + os * __expf(om - nm);
        m = nm;
    }
    float inv = 1.f / (ssum + EPSF);
    if (fits)
        for (int j = lane; j < dg; j += 32)
            vbuf[sl][j] = __expf(vbuf[sl][j] - m) * inv;
    __syncthreads();

    float acc0 = 0.f, acc1 = 0.f;
    const float* hL = h2 + lane;
    if (fits){
        int j = 0;
        for (; j + 3 < dg; j += 4){
            int s0 = sbuf[sl][j], s1 = sbuf[sl][j+1], s2 = sbuf[sl][j+2], s3 = sbuf[sl][j+3];
            float w0 = vbuf[sl][j], w1 = vbuf[sl][j+1], w2 = vbuf[sl][j+2], w3 = vbuf[sl][j+3];
            float g0 = hL[(size_t)s0 * C2], g1 = hL[(size_t)s1 * C2];
            float g2 = hL[(size_t)s2 * C2], g3 = hL[(size_t)s3 * C2];
            acc0 = fmaf(g0, w0, acc0);
            acc1 = fmaf(g1, w1, acc1);
            acc0 = fmaf(g2, w2, acc0);
            acc1 = fmaf(g3, w3, acc1);
        }
        for (; j < dg; ++j)
            acc0 = fmaf(hL[(size_t)sbuf[sl][j] * C2], vbuf[sl][j], acc0);
    } else {
        for (int j = 0; j < dg; ++j){
            int s = srcs[start + j];
            acc0 = fmaf(hL[(size_t)s * C2], __expf(lrelu(as[s] + adv) - m) * inv, acc0);
        }
    }
    out[(size_t)node * C2 + lane] = acc0 + acc1 + b2[lane];
}

extern "C" void kernel_launch(void* const* d_in, const int* in_sizes, int n_in,
                              void* d_out, int out_size, void* d_ws, size_t ws_size,
                              hipStream_t stream) {
    const float* x    = (const float*)d_in[0];
    const int*   ei   = (const int*)  d_in[1];
    const float* W1   = (const float*)d_in[2];
    const float* as1w = (const float*)d_in[3];
    const float* ad1w = (const float*)d_in[4];
    const float* b1   = (const float*)d_in[5];
    const float* W2   = (const float*)d_in[6];
    const float* as2w = (const float*)d_in[7];
    const float* ad2w = (const float*)d_in[8];
    const float* b2   = (const float*)d_in[9];
    float* out = (float*)d_out;

    float* p = (float*)d_ws;
    float* h1   = p; p += (size_t)NN * C1;
    float* hp   = p; p += (size_t)NN * C1;
    float* as1  = p; p += (size_t)NN * H1;
    float* ad1  = p; p += (size_t)NN * H1;
    float* h2   = p; p += (size_t)NN * C2;
    float* as2  = p; p += NN;
    float* ad2  = p; p += NN;
    int* deg  = (int*)p; p += NN;
    int* rows = (int*)p; p += NN;
    int* bcur = (int*)p; p += NBKT;
    int* srcs = (int*)p; p += NE;
    int* bsum = (int*)p; p += 256;
    int2* pairs = (int2*)h1;   // alias: pairs only live before k_gemm1 writes h1

    dim3 B(256);
    // CSR build (2-level counting sort)
    hipMemsetAsync(deg, 0, NN * sizeof(int), stream);
    k_deg   <<<(NE + 255) / 256, B, 0, stream>>>(ei, deg);
    k_scanA <<<NB, B, 0, stream>>>(deg, rows, bsum);
    k_scanB <<<1, B, 0, stream>>>(bsum);
    k_scanC <<<NB, B, 0, stream>>>(rows, bsum);
    k_binit <<<(NBKT + 255) / 256, B, 0, stream>>>(rows, bcur);
    k_part1 <<<NPB1, B, 0, stream>>>(ei, bcur, pairs);
    k_part2 <<<NBKT, B, 0, stream>>>(pairs, rows, srcs);
    // layer 1
    k_gemm1 <<<(NN + 63) / 64, B, 0, stream>>>(x, W1, as1w, ad1w, h1, as1, ad1);
    k_agg1  <<<NN / 4, B, 0, stream>>>(srcs, rows, deg, h1, as1, ad1, b1, hp);
    // layer 2
    k_gemm2 <<<(NN + 127) / 128, B, 0, stream>>>(hp, W2, as2w, ad2w, h2, as2, ad2);
    k_agg2  <<<NN / 8, B, 0, stream>>>(srcs, rows, deg, h2, as2, ad2, b2, out);
}

// Round 6
// 205.066 us; speedup vs baseline: 3.1558x; 1.1992x over previous
//
#include <hip/hip_runtime.h>
#include <math.h>

#define NN 50000
#define NE 800000
#define INCH 128
#define HID1 16
#define H1 4
#define C1 64      /* HEADS*HID */
#define C2 32
#define NEG 0.2f
#define EPSF 1e-16f
#define CAP 128    /* per-node staged-edge cap; deg ~ Poisson(16) */
#define BSH 7      /* 128 nodes per coarse bucket */
#define NBKT 391   /* ceil(NN/128) */
#define CAPB 3072  /* slots per bucket region; mean 2048, +22 sigma */
#define EPB 2048   /* edges per k_part1 block */
#define NPB1 391   /* ceil(NE/EPB) */

static __device__ __forceinline__ float lrelu(float v){ return v > 0.f ? v : NEG * v; }

// ---------------- CSR build (bucket-padded, no global scan) ----------------

// coarse partition: group edges by bucket per block, one global atomic per (block,bucket)
__global__ __launch_bounds__(256) void k_part1(const int* __restrict__ ei, int* bcnt,
                                               int2* __restrict__ pairs){
    __shared__ int hist[512];
    __shared__ int scn[512];
    __shared__ int spos[512];
    __shared__ int gbase[NBKT];
    __shared__ int2 stg[EPB];
    int t = threadIdx.x;
    hist[t] = 0; hist[t + 256] = 0;
    __syncthreads();

    int e0 = blockIdx.x * EPB;
    int tot = NE - e0; if (tot > EPB) tot = EPB;
    int srcv[8], dstv[8], rnk[8], bkt[8];
    #pragma unroll
    for (int k = 0; k < 8; ++k){
        int idx = k * 256 + t;
        if (idx < tot){
            int e = e0 + idx;
            srcv[k] = ei[e];
            dstv[k] = ei[NE + e];
            bkt[k] = dstv[k] >> BSH;
            rnk[k] = atomicAdd(&hist[bkt[k]], 1);
        } else bkt[k] = -1;
    }
    __syncthreads();

    // inclusive scan over 512 slots (ping-pong)
    int* sA = hist; int* sB = scn;
    for (int off = 1; off < 512; off <<= 1){
        int v0 = sA[t]       + ((t       >= off) ? sA[t - off]       : 0);
        int v1 = sA[t + 256] + ((t + 256 >= off) ? sA[t + 256 - off] : 0);
        __syncthreads();
        sB[t] = v0; sB[t + 256] = v1;
        __syncthreads();
        int* tmp = sA; sA = sB; sB = tmp;
    }
    for (int b = t; b < NBKT; b += 256){
        int incl = sA[b];
        int excl = (b > 0) ? sA[b - 1] : 0;
        spos[b] = excl;
        int cnt = incl - excl;
        gbase[b] = (cnt > 0) ? atomicAdd(&bcnt[b], cnt) : 0;
    }
    __syncthreads();

    #pragma unroll
    for (int k = 0; k < 8; ++k)
        if (bkt[k] >= 0){
            int2 pr; pr.x = srcv[k]; pr.y = dstv[k];
            stg[spos[bkt[k]] + rnk[k]] = pr;
        }
    __syncthreads();

    for (int i = t; i < tot; i += 256){
        int2 pr = stg[i];
        int b = pr.y >> BSH;
        pairs[(size_t)b * CAPB + gbase[b] + (i - spos[b])] = pr;
    }
}

// per-bucket: LDS node-histogram + scan -> rows/deg, then LDS-cursor scatter
__global__ __launch_bounds__(256) void k_part2(const int2* __restrict__ pairs,
                                               const int* __restrict__ bcnt,
                                               int* __restrict__ rows, int* __restrict__ deg,
                                               int* __restrict__ srcs){
    __shared__ int2 stg[CAPB];
    __shared__ int hist[128], scn[128], cur[128];
    int b = blockIdx.x, t = threadIdx.x;
    int n0 = b << BSH;
    int cnt = bcnt[b];
    if (t < 128) hist[t] = 0;
    __syncthreads();
    const int2* psrc = pairs + (size_t)b * CAPB;
    for (int i = t; i < cnt; i += 256){
        int2 pr = psrc[i];
        stg[i] = pr;
        atomicAdd(&hist[pr.y - n0], 1);
    }
    __syncthreads();
    int v = (t < 128) ? hist[t] : 0;
    if (t < 128) scn[t] = v;
    __syncthreads();
    for (int off = 1; off < 128; off <<= 1){
        int add = (t < 128 && t >= off) ? scn[t - off] : 0;
        __syncthreads();
        if (t < 128) scn[t] += add;
        __syncthreads();
    }
    if (t < 128){
        int base = b * CAPB + (scn[t] - v);
        cur[t] = base;
        int n = n0 + t;
        if (n < NN){ rows[n] = base; deg[n] = v; }
    }
    __syncthreads();
    for (int i = t; i < cnt; i += 256){
        int2 pr = stg[i];
        int p = atomicAdd(&cur[pr.y - n0], 1);
        srcs[p] = pr.x;
    }
}

// ---- GEMM 1: [NN,128]x[128,64], 64x64 tile, fused alpha1 epilogue ----

__global__ void k_gemm1(const float* __restrict__ x, const float* __restrict__ W,
                        const float* __restrict__ asrc, const float* __restrict__ adst,
                        float* __restrict__ h, float* __restrict__ as1, float* __restrict__ ad1){
    __shared__ float XT[INCH][68];
    __shared__ float WS[INCH * C1];
    __shared__ float ps[64][17];
    __shared__ float pd[64][17];

    int t = threadIdx.x;
    int nodeL = t >> 2;
    int kc = t & 3;
    int g = blockIdx.x * 64 + nodeL;
    int gc = min(g, NN - 1);
    const float4* xr = (const float4*)(x + (size_t)gc * INCH);
    #pragma unroll
    for (int i = 0; i < 8; ++i){
        int k = kc * 32 + i * 4;
        float4 v = xr[k >> 2];
        XT[k + 0][nodeL] = v.x;
        XT[k + 1][nodeL] = v.y;
        XT[k + 2][nodeL] = v.z;
        XT[k + 3][nodeL] = v.w;
    }
    const float4* W4 = (const float4*)W;
    float4* WS4 = (float4*)WS;
    #pragma unroll
    for (int i = 0; i < 8; ++i) WS4[i * 256 + t] = W4[i * 256 + t];
    __syncthreads();

    int tx = t & 15, ty = t >> 4;
    int c4 = tx * 4, n4 = ty * 4;
    float acc[4][4];
    #pragma unroll
    for (int a = 0; a < 4; ++a)
        #pragma unroll
        for (int b = 0; b < 4; ++b) acc[a][b] = 0.f;

    #pragma unroll 8
    for (int k = 0; k < INCH; ++k){
        float4 xa = *(const float4*)&XT[k][n4];
        float4 wb = *(const float4*)&WS[k * C1 + c4];
        const float xv[4] = {xa.x, xa.y, xa.z, xa.w};
        const float wv[4] = {wb.x, wb.y, wb.z, wb.w};
        #pragma unroll
        for (int a = 0; a < 4; ++a)
            #pragma unroll
            for (int b = 0; b < 4; ++b)
                acc[a][b] = fmaf(xv[a], wv[b], acc[a][b]);
    }

    int hd = tx >> 2;
    #pragma unroll
    for (int a = 0; a < 4; ++a){
        int n = blockIdx.x * 64 + n4 + a;
        if (n < NN){
            float4 o = {acc[a][0], acc[a][1], acc[a][2], acc[a][3]};
            *(float4*)&h[(size_t)n * C1 + c4] = o;
        }
        float sa = 0.f, da = 0.f;
        #pragma unroll
        for (int b = 0; b < 4; ++b){
            float wsv = asrc[hd * HID1 + (c4 & 15) + b];
            float wdv = adst[hd * HID1 + (c4 & 15) + b];
            sa = fmaf(acc[a][b], wsv, sa);
            da = fmaf(acc[a][b], wdv, da);
        }
        ps[n4 + a][tx] = sa;
        pd[n4 + a][tx] = da;
    }
    __syncthreads();
    int nd = t & 63, hh = t >> 6;
    int g2 = blockIdx.x * 64 + nd;
    if (g2 < NN){
        float sa = ps[nd][hh*4+0] + ps[nd][hh*4+1] + ps[nd][hh*4+2] + ps[nd][hh*4+3];
        float da = pd[nd][hh*4+0] + pd[nd][hh*4+1] + pd[nd][hh*4+2] + pd[nd][hh*4+3];
        as1[g2 * H1 + hh] = sa;
        ad1[g2 * H1 + hh] = da;
    }
}

// ---- GEMM 2: [NN,64]x[64,32], 128x32 tile, fused alpha2 epilogue ----

__global__ void k_gemm2(const float* __restrict__ hp, const float* __restrict__ W2,
                        const float* __restrict__ asrc, const float* __restrict__ adst,
                        float* __restrict__ h2, float* __restrict__ as2, float* __restrict__ ad2){
    __shared__ float XT[C1][132];
    __shared__ float WS[C1 * C2];
    __shared__ float ps[128][9];
    __shared__ float pd[128][9];

    int t = threadIdx.x;
    int nodeL = t >> 1;
    int kc = t & 1;
    int g = blockIdx.x * 128 + nodeL;
    int gc = min(g, NN - 1);
    const float4* xr = (const float4*)(hp + (size_t)gc * C1);
    #pragma unroll
    for (int i = 0; i < 8; ++i){
        int k = kc * 32 + i * 4;
        float4 v = xr[k >> 2];
        XT[k + 0][nodeL] = v.x;
        XT[k + 1][nodeL] = v.y;
        XT[k + 2][nodeL] = v.z;
        XT[k + 3][nodeL] = v.w;
    }
    const float4* W4 = (const float4*)W2;
    float4* WS4 = (float4*)WS;
    #pragma unroll
    for (int i = 0; i < 2; ++i) WS4[i * 256 + t] = W4[i * 256 + t];
    __syncthreads();

    int tx = t & 7, ty = t >> 3;
    int c4 = tx * 4, n4 = ty * 4;
    float acc[4][4];
    #pragma unroll
    for (int a = 0; a < 4; ++a)
        #pragma unroll
        for (int b = 0; b < 4; ++b) acc[a][b] = 0.f;

    #pragma unroll 8
    for (int k = 0; k < C1; ++k){
        float4 xa = *(const float4*)&XT[k][n4];
        float4 wb = *(const float4*)&WS[k * C2 + c4];
        const float xv[4] = {xa.x, xa.y, xa.z, xa.w};
        const float wv[4] = {wb.x, wb.y, wb.z, wb.w};
        #pragma unroll
        for (int a = 0; a < 4; ++a)
            #pragma unroll
            for (int b = 0; b < 4; ++b)
                acc[a][b] = fmaf(xv[a], wv[b], acc[a][b]);
    }

    #pragma unroll
    for (int a = 0; a < 4; ++a){
        int n = blockIdx.x * 128 + n4 + a;
        if (n < NN){
            float4 o = {acc[a][0], acc[a][1], acc[a][2], acc[a][3]};
            *(float4*)&h2[(size_t)n * C2 + c4] = o;
        }
        float sa = 0.f, da = 0.f;
        #pragma unroll
        for (int b = 0; b < 4; ++b){
            sa = fmaf(acc[a][b], asrc[c4 + b], sa);
            da = fmaf(acc[a][b], adst[c4 + b], da);
        }
        ps[n4 + a][tx] = sa;
        pd[n4 + a][tx] = da;
    }
    __syncthreads();
    if (t < 128){
        int n = blockIdx.x * 128 + t;
        if (n < NN){
            float sa = 0.f, da = 0.f;
            #pragma unroll
            for (int i = 0; i < 8; ++i){ sa += ps[t][i]; da += pd[t][i]; }
            as2[n] = sa;
            ad2[n] = da;
        }
    }
}

// ---------------- aggregation (3-phase, LDS-staged weights) ----------------

__global__ __launch_bounds__(256) void k_agg1(
        const int* __restrict__ srcs, const int* __restrict__ rows,
        const int* __restrict__ deg, const float* __restrict__ h,
        const float* __restrict__ as, const float* __restrict__ ad,
        const float* __restrict__ b1, float* __restrict__ hp){
    __shared__ float vbuf[4][CAP * H1];
    __shared__ int   sbuf[4][CAP];
    __shared__ float minv[4][8];
    int wv = threadIdx.x >> 6;
    int lane = threadIdx.x & 63;
    int node = blockIdx.x * 4 + wv;
    int hd = lane >> 4, sub = lane & 15;
    int start = rows[node], dg = deg[node];
    float adv = ad[node * H1 + hd];
    bool fits = (dg <= CAP);

    float m = -1e30f, ssum = 0.f;
    for (int j = sub; j < dg; j += 16){
        int s = srcs[start + j];
        float v = lrelu(as[s * H1 + hd] + adv);
        if (fits){
            vbuf[wv][j * H1 + hd] = v;
            if (hd == 0) sbuf[wv][j] = s;
        }
        float nm = fmaxf(m, v);
        ssum = ssum * __expf(m - nm) + __expf(v - nm);
        m = nm;
    }
    #pragma unroll
    for (int off = 1; off < 16; off <<= 1){
        float om = __shfl_xor(m, off);
        float os = __shfl_xor(ssum, off);
        float nm = fmaxf(m, om);
        ssum = ssum * __expf(m - nm) + os * __expf(om - nm);
        m = nm;
    }
    float inv = 1.f / (ssum + EPSF);
    if (sub == 0){ minv[wv][hd] = m; minv[wv][4 + hd] = inv; }
    __syncthreads();

    if (fits){
        int tot = dg * H1;
        for (int it = lane; it < tot; it += 64){
            int th = it & 3;
            vbuf[wv][it] = __expf(vbuf[wv][it] - minv[wv][th]) * minv[wv][4 + th];
        }
    }
    __syncthreads();

    float acc0 = 0.f, acc1 = 0.f;
    const float* hL = h + lane;
    if (fits){
        int j = 0;
        for (; j + 3 < dg; j += 4){
            int s0 = sbuf[wv][j], s1 = sbuf[wv][j+1], s2 = sbuf[wv][j+2], s3 = sbuf[wv][j+3];
            float w0 = vbuf[wv][(j+0)*H1+hd], w1 = vbuf[wv][(j+1)*H1+hd];
            float w2 = vbuf[wv][(j+2)*H1+hd], w3 = vbuf[wv][(j+3)*H1+hd];
            float g0 = hL[(size_t)s0 * C1], g1 = hL[(size_t)s1 * C1];
            float g2 = hL[(size_t)s2 * C1], g3 = hL[(size_t)s3 * C1];
            acc0 = fmaf(g0, w0, acc0);
            acc1 = fmaf(g1, w1, acc1);
            acc0 = fmaf(g2, w2, acc0);
            acc1 = fmaf(g3, w3, acc1);
        }
        for (; j < dg; ++j)
            acc0 = fmaf(hL[(size_t)sbuf[wv][j] * C1], vbuf[wv][j*H1+hd], acc0);
    } else {
        for (int j = 0; j < dg; ++j){
            int s = srcs[start + j];
            float v = lrelu(as[s * H1 + hd] + adv);
            acc0 = fmaf(hL[(size_t)s * C1], __expf(v - m) * inv, acc0);
        }
    }
    float o = acc0 + acc1 + b1[lane];
    hp[(size_t)node * C1 + lane] = o > 0.f ? o : expm1f(o);
}

__global__ __launch_bounds__(256) void k_agg2(
        const int* __restrict__ srcs, const int* __restrict__ rows,
        const int* __restrict__ deg, const float* __restrict__ h2,
        const float* __restrict__ as, const float* __restrict__ ad,
        const float* __restrict__ b2, float* __restrict__ out){
    __shared__ float vbuf[8][CAP];
    __shared__ int   sbuf[8][CAP];
    int sl = threadIdx.x >> 5;
    int lane = threadIdx.x & 31;
    int node = blockIdx.x * 8 + sl;
    int start = rows[node], dg = deg[node];
    float adv = ad[node];
    bool fits = (dg <= CAP);

    float m = -1e30f, ssum = 0.f;
    for (int j = lane; j < dg; j += 32){
        int s = srcs[start + j];
        float v = lrelu(as[s] + adv);
        if (fits){ vbuf[sl][j] = v; sbuf[sl][j] = s; }
        float nm = fmaxf(m, v);
        ssum = ssum * __expf(m - nm) + __expf(v - nm);
        m = nm;
    }
    #pragma unroll
    for (int off = 1; off < 32; off <<= 1){
        float om = __shfl_xor(m, off);
        float os = __shfl_xor(ssum, off);
        float nm = fmaxf(m, om);
        ssum = ssum * __expf(m - nm) + os * __expf(om - nm);
        m = nm;
    }
    float inv = 1.f / (ssum + EPSF);
    if (fits)
        for (int j = lane; j < dg; j += 32)
            vbuf[sl][j] = __expf(vbuf[sl][j] - m) * inv;
    __syncthreads();

    float acc0 = 0.f, acc1 = 0.f;
    const float* hL = h2 + lane;
    if (fits){
        int j = 0;
        for (; j + 3 < dg; j += 4){
            int s0 = sbuf[sl][j], s1 = sbuf[sl][j+1], s2 = sbuf[sl][j+2], s3 = sbuf[sl][j+3];
            float w0 = vbuf[sl][j], w1 = vbuf[sl][j+1], w2 = vbuf[sl][j+2], w3 = vbuf[sl][j+3];
            float g0 = hL[(size_t)s0 * C2], g1 = hL[(size_t)s1 * C2];
            float g2 = hL[(size_t)s2 * C2], g3 = hL[(size_t)s3 * C2];
            acc0 = fmaf(g0, w0, acc0);
            acc1 = fmaf(g1, w1, acc1);
            acc0 = fmaf(g2, w2, acc0);
            acc1 = fmaf(g3, w3, acc1);
        }
        for (; j < dg; ++j)
            acc0 = fmaf(hL[(size_t)sbuf[sl][j] * C2], vbuf[sl][j], acc0);
    } else {
        for (int j = 0; j < dg; ++j){
            int s = srcs[start + j];
            acc0 = fmaf(hL[(size_t)s * C2], __expf(lrelu(as[s] + adv) - m) * inv, acc0);
        }
    }
    out[(size_t)node * C2 + lane] = acc0 + acc1 + b2[lane];
}

extern "C" void kernel_launch(void* const* d_in, const int* in_sizes, int n_in,
                              void* d_out, int out_size, void* d_ws, size_t ws_size,
                              hipStream_t stream) {
    const float* x    = (const float*)d_in[0];
    const int*   ei   = (const int*)  d_in[1];
    const float* W1   = (const float*)d_in[2];
    const float* as1w = (const float*)d_in[3];
    const float* ad1w = (const float*)d_in[4];
    const float* b1   = (const float*)d_in[5];
    const float* W2   = (const float*)d_in[6];
    const float* as2w = (const float*)d_in[7];
    const float* ad2w = (const float*)d_in[8];
    const float* b2   = (const float*)d_in[9];
    float* out = (float*)d_out;

    float* p = (float*)d_ws;
    float* h1   = p; p += (size_t)NN * C1;
    float* hp   = p; p += (size_t)NN * C1;
    float* as1  = p; p += (size_t)NN * H1;
    float* ad1  = p; p += (size_t)NN * H1;
    float* h2   = p; p += (size_t)NN * C2;
    float* as2  = p; p += NN;
    float* ad2  = p; p += NN;
    int* deg  = (int*)p; p += NN;
    int* rows = (int*)p; p += NN;
    int* bcnt = (int*)p; p += NBKT;
    int* srcs = (int*)p; p += (size_t)NBKT * CAPB;
    int2* pairs = (int2*)h1;   // alias: pairs (9.6 MB) die before k_gemm1 writes h1 (12.8 MB)

    dim3 B(256);
    // CSR build (bucket-padded 2-level counting sort; no global scan)
    hipMemsetAsync(bcnt, 0, NBKT * sizeof(int), stream);
    k_part1 <<<NPB1, B, 0, stream>>>(ei, bcnt, pairs);
    k_part2 <<<NBKT, B, 0, stream>>>(pairs, bcnt, rows, deg, srcs);
    // layer 1
    k_gemm1 <<<(NN + 63) / 64, B, 0, stream>>>(x, W1, as1w, ad1w, h1, as1, ad1);
    k_agg1  <<<NN / 4, B, 0, stream>>>(srcs, rows, deg, h1, as1, ad1, b1, hp);
    // layer 2
    k_gemm2 <<<(NN + 127) / 128, B, 0, stream>>>(hp, W2, as2w, ad2w, h2, as2, ad2);
    k_agg2  <<<NN / 8, B, 0, stream>>>(srcs, rows, deg, h2, as2, ad2, b2, out);
}

// Round 7
// 197.524 us; speedup vs baseline: 3.2763x; 1.0382x over previous
//
#include <hip/hip_runtime.h>
#include <math.h>

#define NN 50000
#define NE 800000
#define INCH 128
#define HID1 16
#define H1 4
#define C1 64      /* HEADS*HID */
#define C2 32
#define NEG 0.2f
#define EPSF 1e-16f
#define BSH 7      /* 128 nodes per coarse bucket */
#define NBKT 391   /* ceil(NN/128) */
#define CAPB 3072  /* slots per bucket region; mean 2048, +22 sigma */
#define EPB 2048   /* edges per k_part1 block */
#define NPB1 391   /* ceil(NE/EPB) */
#define GB1 782    /* gemm1 blocks = ceil(NN/64) */

static __device__ __forceinline__ float lrelu(float v){ return v > 0.f ? v : NEG * v; }

// ---------------- coarse partition ----------------

__global__ __launch_bounds__(256) void k_part1(const int* __restrict__ ei, int* bcnt,
                                               int2* __restrict__ pairs){
    __shared__ int hist[512];
    __shared__ int scn[512];
    __shared__ int spos[512];
    __shared__ int gbase[NBKT];
    __shared__ int2 stg[EPB];
    int t = threadIdx.x;
    hist[t] = 0; hist[t + 256] = 0;
    __syncthreads();

    int e0 = blockIdx.x * EPB;
    int tot = NE - e0; if (tot > EPB) tot = EPB;
    int srcv[8], dstv[8], rnk[8], bkt[8];
    #pragma unroll
    for (int k = 0; k < 8; ++k){
        int idx = k * 256 + t;
        if (idx < tot){
            int e = e0 + idx;
            srcv[k] = ei[e];
            dstv[k] = ei[NE + e];
            bkt[k] = dstv[k] >> BSH;
            rnk[k] = atomicAdd(&hist[bkt[k]], 1);
        } else bkt[k] = -1;
    }
    __syncthreads();

    int* sA = hist; int* sB = scn;
    for (int off = 1; off < 512; off <<= 1){
        int v0 = sA[t]       + ((t       >= off) ? sA[t - off]       : 0);
        int v1 = sA[t + 256] + ((t + 256 >= off) ? sA[t + 256 - off] : 0);
        __syncthreads();
        sB[t] = v0; sB[t + 256] = v1;
        __syncthreads();
        int* tmp = sA; sA = sB; sB = tmp;
    }
    for (int b = t; b < NBKT; b += 256){
        int incl = sA[b];
        int excl = (b > 0) ? sA[b - 1] : 0;
        spos[b] = excl;
        int cnt = incl - excl;
        gbase[b] = (cnt > 0) ? atomicAdd(&bcnt[b], cnt) : 0;
    }
    __syncthreads();

    #pragma unroll
    for (int k = 0; k < 8; ++k)
        if (bkt[k] >= 0){
            int2 pr; pr.x = srcv[k]; pr.y = dstv[k];
            stg[spos[bkt[k]] + rnk[k]] = pr;
        }
    __syncthreads();

    for (int i = t; i < tot; i += 256){
        int2 pr = stg[i];
        int b = pr.y >> BSH;
        pairs[(size_t)b * CAPB + gbase[b] + (i - spos[b])] = pr;
    }
}

// ---------------- fused: part2 (fine scatter) UNION gemm1(+alpha1) ----------------
// blocks [0, NBKT): per-bucket scatter; blocks [NBKT, NBKT+GB1): gemm1 64x64 tile

__global__ __launch_bounds__(256) void k_build2(
        const int2* __restrict__ pairs, const int* __restrict__ bcnt,
        int* __restrict__ rows, int* __restrict__ deg, int* __restrict__ srcs,
        const float* __restrict__ x, const float* __restrict__ W,
        const float* __restrict__ asrc, const float* __restrict__ adst,
        float* __restrict__ h, float* __restrict__ as1, float* __restrict__ ad1){
    __shared__ __align__(16) char smem[76288];
    int t = threadIdx.x;

    if (blockIdx.x < NBKT){
        // ---- part2 ----
        int2* stg = (int2*)smem;                     // 24576 B
        int* hist = (int*)(smem + 24576);            // 512 B
        int* scn  = (int*)(smem + 25088);            // 512 B
        int* cur  = (int*)(smem + 25600);            // 512 B
        int b = blockIdx.x;
        int n0 = b << BSH;
        int cnt = bcnt[b];
        if (t < 128) hist[t] = 0;
        __syncthreads();
        const int2* psrc = pairs + (size_t)b * CAPB;
        for (int i = t; i < cnt; i += 256){
            int2 pr = psrc[i];
            stg[i] = pr;
            atomicAdd(&hist[pr.y - n0], 1);
        }
        __syncthreads();
        int v = (t < 128) ? hist[t] : 0;
        if (t < 128) scn[t] = v;
        __syncthreads();
        for (int off = 1; off < 128; off <<= 1){
            int add = (t < 128 && t >= off) ? scn[t - off] : 0;
            __syncthreads();
            if (t < 128) scn[t] += add;
            __syncthreads();
        }
        if (t < 128){
            int base = b * CAPB + (scn[t] - v);
            cur[t] = base;
            int n = n0 + t;
            if (n < NN){ rows[n] = base; deg[n] = v; }
        }
        __syncthreads();
        for (int i = t; i < cnt; i += 256){
            int2 pr = stg[i];
            int p = atomicAdd(&cur[pr.y - n0], 1);
            srcs[p] = pr.x;
        }
    } else {
        // ---- gemm1 + alpha1 ----
        float (*XT)[68] = (float(*)[68])smem;                         // 34816 B
        float* WS = (float*)(smem + 34816);                           // 32768 B
        float (*ps)[17] = (float(*)[17])(smem + 67584);               // 4352 B
        float (*pd)[17] = (float(*)[17])(smem + 71936);               // 4352 B
        int bid = blockIdx.x - NBKT;

        int nodeL = t >> 2;
        int kc = t & 3;
        int g = bid * 64 + nodeL;
        int gc = min(g, NN - 1);
        const float4* xr = (const float4*)(x + (size_t)gc * INCH);
        #pragma unroll
        for (int i = 0; i < 8; ++i){
            int k = kc * 32 + i * 4;
            float4 v = xr[k >> 2];
            XT[k + 0][nodeL] = v.x;
            XT[k + 1][nodeL] = v.y;
            XT[k + 2][nodeL] = v.z;
            XT[k + 3][nodeL] = v.w;
        }
        const float4* W4 = (const float4*)W;
        float4* WS4 = (float4*)WS;
        #pragma unroll
        for (int i = 0; i < 8; ++i) WS4[i * 256 + t] = W4[i * 256 + t];
        __syncthreads();

        int tx = t & 15, ty = t >> 4;
        int c4 = tx * 4, n4 = ty * 4;
        float acc[4][4];
        #pragma unroll
        for (int a = 0; a < 4; ++a)
            #pragma unroll
            for (int b2 = 0; b2 < 4; ++b2) acc[a][b2] = 0.f;

        #pragma unroll 8
        for (int k = 0; k < INCH; ++k){
            float4 xa = *(const float4*)&XT[k][n4];
            float4 wb = *(const float4*)&WS[k * C1 + c4];
            const float xv[4] = {xa.x, xa.y, xa.z, xa.w};
            const float wv[4] = {wb.x, wb.y, wb.z, wb.w};
            #pragma unroll
            for (int a = 0; a < 4; ++a)
                #pragma unroll
                for (int b2 = 0; b2 < 4; ++b2)
                    acc[a][b2] = fmaf(xv[a], wv[b2], acc[a][b2]);
        }

        int hd = tx >> 2;
        #pragma unroll
        for (int a = 0; a < 4; ++a){
            int n = bid * 64 + n4 + a;
            if (n < NN){
                float4 o = {acc[a][0], acc[a][1], acc[a][2], acc[a][3]};
                *(float4*)&h[(size_t)n * C1 + c4] = o;
            }
            float sa = 0.f, da = 0.f;
            #pragma unroll
            for (int b2 = 0; b2 < 4; ++b2){
                sa = fmaf(acc[a][b2], asrc[hd * HID1 + (c4 & 15) + b2], sa);
                da = fmaf(acc[a][b2], adst[hd * HID1 + (c4 & 15) + b2], da);
            }
            ps[n4 + a][tx] = sa;
            pd[n4 + a][tx] = da;
        }
        __syncthreads();
        int nd = t & 63, hh = t >> 6;
        int g2 = bid * 64 + nd;
        if (g2 < NN){
            float sa = ps[nd][hh*4+0] + ps[nd][hh*4+1] + ps[nd][hh*4+2] + ps[nd][hh*4+3];
            float da = pd[nd][hh*4+0] + pd[nd][hh*4+1] + pd[nd][hh*4+2] + pd[nd][hh*4+3];
            as1[g2 * H1 + hh] = sa;
            ad1[g2 * H1 + hh] = da;
        }
    }
}

// ---------------- fused: agg1 (single-pass, no-max softmax) + ELU + gemm2(+alpha2) ----------------
// block = 256 threads = 16 nodes; each wave serially processes 4 nodes (1 wave-pass each);
// hp tile lives only in LDS; gemm2 phase: 2 outputs/thread; alpha2 via 16-lane shuffle.

__global__ __launch_bounds__(256) void k_aggA(
        const int* __restrict__ srcs, const int* __restrict__ rows,
        const int* __restrict__ deg, const float* __restrict__ h1,
        const float* __restrict__ as, const float* __restrict__ ad,
        const float* __restrict__ b1, const float* __restrict__ W2,
        const float* __restrict__ a2s, const float* __restrict__ a2d,
        float* __restrict__ h2, float* __restrict__ as2, float* __restrict__ ad2){
    __shared__ float hpT[16][65];
    __shared__ float WS[C1 * C2];
    int t = threadIdx.x;
    {   // stage W2 (no barrier needed until gemm2 phase)
        const float4* W4 = (const float4*)W2;
        float4* WS4 = (float4*)WS;
        WS4[t] = W4[t];
        WS4[256 + t] = W4[256 + t];
    }
    int w = t >> 6, lane = t & 63, hd = lane >> 4;
    float bv = b1[lane];
    #pragma unroll
    for (int q = 0; q < 4; ++q){
        int node = blockIdx.x * 16 + w * 4 + q;
        int start = rows[node], dg = deg[node];
        float adv = ad[node * H1 + hd];
        const float* hL = h1 + lane;
        float ss0 = 0.f, ss1 = 0.f, ac0 = 0.f, ac1 = 0.f, ac2 = 0.f, ac3 = 0.f;
        int j = 0;
        for (; j + 3 < dg; j += 4){
            int s0 = srcs[start + j], s1 = srcs[start + j + 1];
            int s2 = srcs[start + j + 2], s3 = srcs[start + j + 3];
            float w0 = __expf(lrelu(as[s0 * H1 + hd] + adv));
            float w1 = __expf(lrelu(as[s1 * H1 + hd] + adv));
            float w2 = __expf(lrelu(as[s2 * H1 + hd] + adv));
            float w3 = __expf(lrelu(as[s3 * H1 + hd] + adv));
            ss0 += w0 + w2; ss1 += w1 + w3;
            ac0 = fmaf(hL[(size_t)s0 * C1], w0, ac0);
            ac1 = fmaf(hL[(size_t)s1 * C1], w1, ac1);
            ac2 = fmaf(hL[(size_t)s2 * C1], w2, ac2);
            ac3 = fmaf(hL[(size_t)s3 * C1], w3, ac3);
        }
        for (; j < dg; ++j){
            int s = srcs[start + j];
            float wv = __expf(lrelu(as[s * H1 + hd] + adv));
            ss0 += wv;
            ac0 = fmaf(hL[(size_t)s * C1], wv, ac0);
        }
        float o = (ac0 + ac1 + ac2 + ac3) / (ss0 + ss1 + EPSF) + bv;
        hpT[w * 4 + q][lane] = o > 0.f ? o : expm1f(o);
    }
    __syncthreads();

    // gemm2 phase: n = t>>4 (0..15), c = t&15; outputs c and c+16
    int n = t >> 4, c = t & 15;
    float a0 = 0.f, a1 = 0.f;
    #pragma unroll 8
    for (int k = 0; k < C1; ++k){
        float hv = hpT[n][k];
        a0 = fmaf(hv, WS[k * C2 + c], a0);
        a1 = fmaf(hv, WS[k * C2 + c + 16], a1);
    }
    int gn = blockIdx.x * 16 + n;
    h2[(size_t)gn * C2 + c] = a0;
    h2[(size_t)gn * C2 + c + 16] = a1;
    float sa = a0 * a2s[c] + a1 * a2s[c + 16];
    float da = a0 * a2d[c] + a1 * a2d[c + 16];
    #pragma unroll
    for (int off = 8; off >= 1; off >>= 1){
        sa += __shfl_xor(sa, off);
        da += __shfl_xor(da, off);
    }
    if (c == 0){ as2[gn] = sa; ad2[gn] = da; }
}

// ---------------- agg2: single-pass, no-max softmax ----------------

__global__ __launch_bounds__(256) void k_agg2(
        const int* __restrict__ srcs, const int* __restrict__ rows,
        const int* __restrict__ deg, const float* __restrict__ h2,
        const float* __restrict__ as, const float* __restrict__ ad,
        const float* __restrict__ b2, float* __restrict__ out){
    int sl = threadIdx.x >> 5;
    int lane = threadIdx.x & 31;
    int node = blockIdx.x * 8 + sl;
    int start = rows[node], dg = deg[node];
    float adv = ad[node];
    const float* hL = h2 + lane;
    float ss0 = 0.f, ss1 = 0.f, ac0 = 0.f, ac1 = 0.f, ac2 = 0.f, ac3 = 0.f;
    int j = 0;
    for (; j + 3 < dg; j += 4){
        int s0 = srcs[start + j], s1 = srcs[start + j + 1];
        int s2 = srcs[start + j + 2], s3 = srcs[start + j + 3];
        float w0 = __expf(lrelu(as[s0] + adv));
        float w1 = __expf(lrelu(as[s1] + adv));
        float w2 = __expf(lrelu(as[s2] + adv));
        float w3 = __expf(lrelu(as[s3] + adv));
        ss0 += w0 + w2; ss1 += w1 + w3;
        ac0 = fmaf(hL[(size_t)s0 * C2], w0, ac0);
        ac1 = fmaf(hL[(size_t)s1 * C2], w1, ac1);
        ac2 = fmaf(hL[(size_t)s2 * C2], w2, ac2);
        ac3 = fmaf(hL[(size_t)s3 * C2], w3, ac3);
    }
    for (; j < dg; ++j){
        int s = srcs[start + j];
        float wv = __expf(lrelu(as[s] + adv));
        ss0 += wv;
        ac0 = fmaf(hL[(size_t)s * C2], wv, ac0);
    }
    out[(size_t)node * C2 + lane] = (ac0 + ac1 + ac2 + ac3) / (ss0 + ss1 + EPSF) + b2[lane];
}

extern "C" void kernel_launch(void* const* d_in, const int* in_sizes, int n_in,
                              void* d_out, int out_size, void* d_ws, size_t ws_size,
                              hipStream_t stream) {
    const float* x    = (const float*)d_in[0];
    const int*   ei   = (const int*)  d_in[1];
    const float* W1   = (const float*)d_in[2];
    const float* as1w = (const float*)d_in[3];
    const float* ad1w = (const float*)d_in[4];
    const float* b1   = (const float*)d_in[5];
    const float* W2   = (const float*)d_in[6];
    const float* as2w = (const float*)d_in[7];
    const float* ad2w = (const float*)d_in[8];
    const float* b2   = (const float*)d_in[9];
    float* out = (float*)d_out;

    float* p = (float*)d_ws;
    float* h1   = p; p += (size_t)NN * C1;
    float* as1  = p; p += (size_t)NN * H1;
    float* ad1  = p; p += (size_t)NN * H1;
    float* h2   = p; p += (size_t)NN * C2;
    float* as2  = p; p += NN;
    float* ad2  = p; p += NN;
    int* deg  = (int*)p; p += NN;
    int* rows = (int*)p; p += NN;
    int* bcnt = (int*)p; p += NBKT + 57;               // pad to 16B alignment
    int* srcs = (int*)p; p += (size_t)NBKT * CAPB;
    int2* pairs = (int2*)p;                            // 9.6 MB, own region (part2 || gemm1)

    dim3 B(256);
    hipMemsetAsync(bcnt, 0, NBKT * sizeof(int), stream);
    k_part1 <<<NPB1, B, 0, stream>>>(ei, bcnt, pairs);
    k_build2<<<NBKT + GB1, B, 0, stream>>>(pairs, bcnt, rows, deg, srcs,
                                           x, W1, as1w, ad1w, h1, as1, ad1);
    k_aggA  <<<NN / 16, B, 0, stream>>>(srcs, rows, deg, h1, as1, ad1, b1,
                                        W2, as2w, ad2w, h2, as2, ad2);
    k_agg2  <<<NN / 8, B, 0, stream>>>(srcs, rows, deg, h2, as2, ad2, b2, out);
}